// Round 1
// baseline (802.006 us; speedup 1.0000x reference)
//
#include <hip/hip_runtime.h>
#include <hip/hip_bf16.h>

#define N_NODES_EXPECT 100000
#define IN_DIM 128
#define OUT_DIM 64

// ---------------------------------------------------------------------------
// K1: degree count: deg[col[e]] += 1
// ---------------------------------------------------------------------------
__global__ void gcn_degree(const int* __restrict__ col, float* __restrict__ deg,
                           int n_edges) {
    int i = blockIdx.x * blockDim.x + threadIdx.x;
    int stride = gridDim.x * blockDim.x;
    for (; i < n_edges; i += stride) {
        atomicAdd(&deg[col[i]], 1.0f);
    }
}

// ---------------------------------------------------------------------------
// K2: deg -> deg_inv_sqrt (in place)
// ---------------------------------------------------------------------------
__global__ void gcn_rsqrt(float* __restrict__ deg, int n_nodes) {
    int i = blockIdx.x * blockDim.x + threadIdx.x;
    if (i < n_nodes) {
        float d = deg[i];
        deg[i] = (d > 0.0f) ? rsqrtf(d) : 0.0f;
    }
}

// ---------------------------------------------------------------------------
// K3: h = x @ W   (fp32 vector matmul; wave per node, lane = out column,
//     W column held in registers)
// ---------------------------------------------------------------------------
__global__ void __launch_bounds__(256) gcn_matmul(
    const float* __restrict__ x, const float* __restrict__ W,
    float* __restrict__ h, int n_nodes) {
    const int lane = threadIdx.x & 63;
    const int wid  = (blockIdx.x * blockDim.x + threadIdx.x) >> 6;
    const int nw   = (gridDim.x * blockDim.x) >> 6;

    // each lane holds its output column of W: W[k][lane], k = 0..127
    float w[IN_DIM];
#pragma unroll
    for (int k = 0; k < IN_DIM; ++k) w[k] = W[k * OUT_DIM + lane];

    for (int n = wid; n < n_nodes; n += nw) {
        const float4* xr = (const float4*)(x + (size_t)n * IN_DIM);
        float acc = 0.0f;
#pragma unroll
        for (int k4 = 0; k4 < IN_DIM / 4; ++k4) {
            float4 xv = xr[k4];  // wave-uniform broadcast load
            acc = fmaf(xv.x, w[k4 * 4 + 0], acc);
            acc = fmaf(xv.y, w[k4 * 4 + 1], acc);
            acc = fmaf(xv.z, w[k4 * 4 + 2], acc);
            acc = fmaf(xv.w, w[k4 * 4 + 3], acc);
        }
        h[(size_t)n * OUT_DIM + lane] = acc;
    }
}

// ---------------------------------------------------------------------------
// K4: scatter: out[col[e]][:] += h[row[e]][:] * dis[row[e]] * dis[col[e]]
//     wave per edge, lane = column -> 64 contiguous fp32 atomics per edge
// ---------------------------------------------------------------------------
__global__ void __launch_bounds__(256) gcn_scatter(
    const int* __restrict__ row, const int* __restrict__ col,
    const float* __restrict__ dis, const float* __restrict__ h,
    float* __restrict__ out, int n_edges) {
    const int lane = threadIdx.x & 63;
    int e  = (blockIdx.x * blockDim.x + threadIdx.x) >> 6;
    int nw = (gridDim.x * blockDim.x) >> 6;
    for (; e < n_edges; e += nw) {
        int r = row[e];
        int c = col[e];
        float norm = dis[r] * dis[c];
        float v = h[(size_t)r * OUT_DIM + lane] * norm;
        atomicAdd(&out[(size_t)c * OUT_DIM + lane], v);
    }
}

// ---------------------------------------------------------------------------
// K5: out = relu(out + b)
// ---------------------------------------------------------------------------
__global__ void gcn_bias_relu(float* __restrict__ out, const float* __restrict__ b,
                              int total) {
    int i = blockIdx.x * blockDim.x + threadIdx.x;
    int stride = gridDim.x * blockDim.x;
    for (; i < total; i += stride) {
        float v = out[i] + b[i & (OUT_DIM - 1)];
        out[i] = fmaxf(v, 0.0f);
    }
}

extern "C" void kernel_launch(void* const* d_in, const int* in_sizes, int n_in,
                              void* d_out, int out_size, void* d_ws, size_t ws_size,
                              hipStream_t stream) {
    const float* x  = (const float*)d_in[0];
    const int*   ei = (const int*)d_in[1];   // [2, E] int32 per harness contract
    const float* W  = (const float*)d_in[2];
    const float* b  = (const float*)d_in[3];
    float* out = (float*)d_out;

    const int n_nodes = in_sizes[0] / IN_DIM;
    const int n_edges = in_sizes[1] / 2;
    const int* row = ei;            // edge_index[0]
    const int* col = ei + n_edges;  // edge_index[1]

    // workspace layout: [deg/dis: n_nodes floats][h: n_nodes*64 floats]
    char* wsb = (char*)d_ws;
    float* deg = (float*)wsb;
    size_t h_off = ((size_t)n_nodes * sizeof(float) + 1023) & ~(size_t)1023;
    float* h = (float*)(wsb + h_off);

    // zero-init deg and out (harness poisons them with 0xAA)
    hipMemsetAsync(deg, 0, (size_t)n_nodes * sizeof(float), stream);
    hipMemsetAsync(out, 0, (size_t)out_size * sizeof(float), stream);

    // K1: degree
    gcn_degree<<<2048, 256, 0, stream>>>(col, deg, n_edges);
    // K2: rsqrt
    gcn_rsqrt<<<(n_nodes + 255) / 256, 256, 0, stream>>>(deg, n_nodes);
    // K3: h = x @ W
    gcn_matmul<<<1024, 256, 0, stream>>>(x, W, h, n_nodes);
    // K4: scatter-add messages
    gcn_scatter<<<2048, 256, 0, stream>>>(row, col, deg, h, out, n_edges);
    // K5: bias + relu
    gcn_bias_relu<<<2048, 256, 0, stream>>>(out, b, n_nodes * OUT_DIM);
}

// Round 2
// 442.667 us; speedup vs baseline: 1.8118x; 1.8118x over previous
//
#include <hip/hip_runtime.h>
#include <hip/hip_bf16.h>

#define IN_DIM 128
#define OUT_DIM 64
#define SCAN_BLOCK 1024   // elements per scan block
#define SCAN_TPB 256      // threads per scan block (4 elems/thread)

static inline size_t align_up(size_t v, size_t a) { return (v + a - 1) & ~(a - 1); }

// ---------------------------------------------------------------------------
// K1: degree count (int): deg[col[e]] += 1
// ---------------------------------------------------------------------------
__global__ void k_degree(const int* __restrict__ col, int* __restrict__ deg,
                         int n_edges) {
    int i = blockIdx.x * blockDim.x + threadIdx.x;
    int stride = gridDim.x * blockDim.x;
    for (; i < n_edges; i += stride) atomicAdd(&deg[col[i]], 1);
}

// ---------------------------------------------------------------------------
// K2: dis[i] = deg>0 ? rsqrt(deg) : 0
// ---------------------------------------------------------------------------
__global__ void k_rsqrt(const int* __restrict__ deg, float* __restrict__ dis, int n) {
    int i = blockIdx.x * blockDim.x + threadIdx.x;
    if (i < n) {
        int d = deg[i];
        dis[i] = (d > 0) ? rsqrtf((float)d) : 0.0f;
    }
}

// ---------------------------------------------------------------------------
// Scan pass 1: per-block partial sums of deg (1024 elems / block)
// ---------------------------------------------------------------------------
__global__ void k_scan_partial(const int* __restrict__ deg, int* __restrict__ bsum,
                               int n) {
    __shared__ int s[SCAN_TPB];
    int t = threadIdx.x;
    int base = blockIdx.x * SCAN_BLOCK + t * 4;
    int v = 0;
#pragma unroll
    for (int j = 0; j < 4; ++j) {
        int idx = base + j;
        if (idx < n) v += deg[idx];
    }
    s[t] = v;
    __syncthreads();
    for (int off = SCAN_TPB / 2; off > 0; off >>= 1) {
        if (t < off) s[t] += s[t + off];
        __syncthreads();
    }
    if (t == 0) bsum[blockIdx.x] = s[0];
}

// ---------------------------------------------------------------------------
// Scan pass 2: exclusive scan of block sums (single block, up to 1024 blocks)
// also writes row_start[n_nodes] = n_edges
// ---------------------------------------------------------------------------
__global__ void k_scan_blocksums(int* __restrict__ bsum, int nb,
                                 int* __restrict__ row_start, int n_nodes,
                                 int n_edges) {
    __shared__ int s[1024];
    int t = threadIdx.x;
    int v = (t < nb) ? bsum[t] : 0;
    s[t] = v;
    __syncthreads();
    for (int off = 1; off < 1024; off <<= 1) {
        int x = (t >= off) ? s[t - off] : 0;
        __syncthreads();
        s[t] += x;
        __syncthreads();
    }
    if (t < nb) bsum[t] = s[t] - v;  // exclusive
    if (t == 0) row_start[n_nodes] = n_edges;
}

// ---------------------------------------------------------------------------
// Scan pass 3: full exclusive scan -> row_start and cursor (two copies)
// ---------------------------------------------------------------------------
__global__ void k_scan_final(const int* __restrict__ deg, const int* __restrict__ bsum,
                             int* __restrict__ row_start, int* __restrict__ cursor,
                             int n) {
    __shared__ int s[SCAN_TPB];
    int t = threadIdx.x;
    int base = blockIdx.x * SCAN_BLOCK + t * 4;
    int v[4];
#pragma unroll
    for (int j = 0; j < 4; ++j) {
        int idx = base + j;
        v[j] = (idx < n) ? deg[idx] : 0;
    }
    int tsum = v[0] + v[1] + v[2] + v[3];
    s[t] = tsum;
    __syncthreads();
    for (int off = 1; off < SCAN_TPB; off <<= 1) {
        int x = (t >= off) ? s[t - off] : 0;
        __syncthreads();
        s[t] += x;
        __syncthreads();
    }
    int run = bsum[blockIdx.x] + (s[t] - tsum);  // global exclusive prefix
#pragma unroll
    for (int j = 0; j < 4; ++j) {
        int idx = base + j;
        if (idx < n) {
            row_start[idx] = run;
            cursor[idx] = run;
            run += v[j];
        }
    }
}

// ---------------------------------------------------------------------------
// K3: h = (x @ W) * dis   (fp32; block stages 16 x-rows in LDS, wave=4 nodes,
//     lane = out column, W column in registers)
// ---------------------------------------------------------------------------
#define MM_NODES 16
__global__ void __launch_bounds__(256) k_matmul(
    const float* __restrict__ x, const float* __restrict__ W,
    const float* __restrict__ dis, float* __restrict__ h, int n_nodes) {
    __shared__ float xs[MM_NODES * IN_DIM];  // 8 KB
    const int lane = threadIdx.x & 63;
    const int wv = threadIdx.x >> 6;  // 0..3

    float w[IN_DIM];
#pragma unroll
    for (int k = 0; k < IN_DIM; ++k) w[k] = W[k * OUT_DIM + lane];

    int nchunks = (n_nodes + MM_NODES - 1) / MM_NODES;
    for (int ch = blockIdx.x; ch < nchunks; ch += gridDim.x) {
        int base = ch * MM_NODES;
        int nrows = min(MM_NODES, n_nodes - base);
        __syncthreads();  // protect xs from previous iteration's readers
        const float4* xg = (const float4*)(x + (size_t)base * IN_DIM);
        int nf4 = nrows * IN_DIM / 4;
        for (int i = threadIdx.x; i < nf4; i += 256) ((float4*)xs)[i] = xg[i];
        __syncthreads();
#pragma unroll
        for (int j = 0; j < 4; ++j) {
            int local = wv * 4 + j;
            int node = base + local;
            if (local < nrows) {
                const float4* xr = (const float4*)(xs + local * IN_DIM);
                float acc = 0.0f;
#pragma unroll
                for (int k4 = 0; k4 < IN_DIM / 4; ++k4) {
                    float4 xv = xr[k4];  // LDS broadcast read
                    acc = fmaf(xv.x, w[k4 * 4 + 0], acc);
                    acc = fmaf(xv.y, w[k4 * 4 + 1], acc);
                    acc = fmaf(xv.z, w[k4 * 4 + 2], acc);
                    acc = fmaf(xv.w, w[k4 * 4 + 3], acc);
                }
                h[(size_t)node * OUT_DIM + lane] = acc * dis[node];
            }
        }
    }
}

// ---------------------------------------------------------------------------
// K4: CSR bucket fill: edge_src[pos] = row[e], pos = cursor[col[e]]++
// ---------------------------------------------------------------------------
__global__ void k_fill(const int* __restrict__ row, const int* __restrict__ col,
                       int* __restrict__ cursor, int* __restrict__ edge_src,
                       int n_edges) {
    int i = blockIdx.x * blockDim.x + threadIdx.x;
    int stride = gridDim.x * blockDim.x;
    for (; i < n_edges; i += stride) {
        int pos = atomicAdd(&cursor[col[i]], 1);
        edge_src[pos] = row[i];
    }
}

// ---------------------------------------------------------------------------
// K5: aggregation: out[c] = relu(dis[c] * sum_{r in N(c)} h[r] + b)
//     one wave per target node, lane = out column; register accumulate
// ---------------------------------------------------------------------------
__global__ void __launch_bounds__(256) k_aggregate(
    const int* __restrict__ row_start, const int* __restrict__ edge_src,
    const float* __restrict__ dis, const float* __restrict__ h,
    const float* __restrict__ b, float* __restrict__ out, int n_nodes) {
    const int lane = threadIdx.x & 63;
    int wid = (blockIdx.x * blockDim.x + threadIdx.x) >> 6;
    int nw = (gridDim.x * blockDim.x) >> 6;
    float bias = b[lane];
    for (int c = wid; c < n_nodes; c += nw) {
        int s = row_start[c];
        int e = row_start[c + 1];
        float acc = 0.0f;
        int i = s;
        for (; i + 1 < e; i += 2) {  // unroll-2: two gathers in flight
            int r0 = edge_src[i];
            int r1 = edge_src[i + 1];
            float v0 = h[(size_t)r0 * OUT_DIM + lane];
            float v1 = h[(size_t)r1 * OUT_DIM + lane];
            acc += v0;
            acc += v1;
        }
        if (i < e) acc += h[(size_t)edge_src[i] * OUT_DIM + lane];
        float v = fmaf(acc, dis[c], bias);
        out[(size_t)c * OUT_DIM + lane] = fmaxf(v, 0.0f);
    }
}

// ---------------------------------------------------------------------------
// Fallback path (if workspace too small for CSR): atomic scatter as in R1
// ---------------------------------------------------------------------------
__global__ void __launch_bounds__(256) k_scatter_fb(
    const int* __restrict__ row, const int* __restrict__ col,
    const float* __restrict__ dis, const float* __restrict__ h,
    float* __restrict__ out, int n_edges) {
    const int lane = threadIdx.x & 63;
    int e = (blockIdx.x * blockDim.x + threadIdx.x) >> 6;
    int nw = (gridDim.x * blockDim.x) >> 6;
    for (; e < n_edges; e += nw) {
        int r = row[e];
        int c = col[e];
        float v = h[(size_t)r * OUT_DIM + lane] * dis[c];  // h already has dis[r]
        atomicAdd(&out[(size_t)c * OUT_DIM + lane], v);
    }
}

__global__ void k_bias_relu_fb(float* __restrict__ out, const float* __restrict__ b,
                               int total) {
    int i = blockIdx.x * blockDim.x + threadIdx.x;
    int stride = gridDim.x * blockDim.x;
    for (; i < total; i += stride) {
        float v = out[i] + b[i & (OUT_DIM - 1)];
        out[i] = fmaxf(v, 0.0f);
    }
}

extern "C" void kernel_launch(void* const* d_in, const int* in_sizes, int n_in,
                              void* d_out, int out_size, void* d_ws, size_t ws_size,
                              hipStream_t stream) {
    const float* x = (const float*)d_in[0];
    const int* ei = (const int*)d_in[1];  // [2, E] int32
    const float* W = (const float*)d_in[2];
    const float* b = (const float*)d_in[3];
    float* out = (float*)d_out;

    const int n_nodes = in_sizes[0] / IN_DIM;
    const int n_edges = in_sizes[1] / 2;
    const int* row = ei;
    const int* col = ei + n_edges;

    // ---- workspace layout (CSR path) ----
    char* wsb = (char*)d_ws;
    size_t off = 0;
    int* deg = (int*)(wsb + off);       off += align_up((size_t)n_nodes * 4, 256);
    int* row_start = (int*)(wsb + off); off += align_up((size_t)(n_nodes + 1) * 4, 256);
    int* cursor = (int*)(wsb + off);    off += align_up((size_t)(n_nodes + 1) * 4, 256);
    int* bsum = (int*)(wsb + off);      off += align_up(1024 * 4, 256);
    float* dis = (float*)(wsb + off);   off += align_up((size_t)n_nodes * 4, 256);
    int* edge_src = (int*)(wsb + off);  off += align_up((size_t)n_edges * 4, 256);
    float* h = (float*)(wsb + off);     off += (size_t)n_nodes * OUT_DIM * 4;
    const size_t needed = off;

    const int nb = (n_nodes + SCAN_BLOCK - 1) / SCAN_BLOCK;  // scan blocks (<=1024)

    if (ws_size >= needed && nb <= 1024) {
        // ---- CSR (atomic-free aggregation) path ----
        hipMemsetAsync(deg, 0, (size_t)n_nodes * 4, stream);
        k_degree<<<1024, 256, 0, stream>>>(col, deg, n_edges);
        k_rsqrt<<<(n_nodes + 255) / 256, 256, 0, stream>>>(deg, dis, n_nodes);
        k_scan_partial<<<nb, SCAN_TPB, 0, stream>>>(deg, bsum, n_nodes);
        k_scan_blocksums<<<1, 1024, 0, stream>>>(bsum, nb, row_start, n_nodes, n_edges);
        k_scan_final<<<nb, SCAN_TPB, 0, stream>>>(deg, bsum, row_start, cursor, n_nodes);
        k_matmul<<<1024, 256, 0, stream>>>(x, W, dis, h, n_nodes);
        k_fill<<<1024, 256, 0, stream>>>(row, col, cursor, edge_src, n_edges);
        int agg_blocks = (n_nodes * (OUT_DIM / 4) + 255) / 256 + 1;  // ~1 wave/node
        k_aggregate<<<agg_blocks, 256, 0, stream>>>(row_start, edge_src, dis, h, b,
                                                    out, n_nodes);
    } else {
        // ---- fallback: atomic scatter (R1 structure) ----
        char* p = (char*)d_ws;
        int* deg_f = (int*)p;
        float* dis_f = (float*)(p + align_up((size_t)n_nodes * 4, 256));
        float* h_f = (float*)(p + align_up((size_t)n_nodes * 4, 256) +
                              align_up((size_t)n_nodes * 4, 256));
        hipMemsetAsync(deg_f, 0, (size_t)n_nodes * 4, stream);
        hipMemsetAsync(out, 0, (size_t)out_size * 4, stream);
        k_degree<<<1024, 256, 0, stream>>>(col, deg_f, n_edges);
        k_rsqrt<<<(n_nodes + 255) / 256, 256, 0, stream>>>(deg_f, dis_f, n_nodes);
        k_matmul<<<1024, 256, 0, stream>>>(x, W, dis_f, h_f, n_nodes);
        k_scatter_fb<<<2048, 256, 0, stream>>>(row, col, dis_f, h_f, out, n_edges);
        k_bias_relu_fb<<<2048, 256, 0, stream>>>(out, b, n_nodes * OUT_DIM);
    }
}

// Round 3
// 328.510 us; speedup vs baseline: 2.4413x; 1.3475x over previous
//
#include <hip/hip_runtime.h>
#include <hip/hip_bf16.h>

#define IN_DIM 128
#define OUT_DIM 64
#define SCAN_BLOCK 1024   // elements per scan block
#define SCAN_TPB 256      // threads per scan block (4 elems/thread)

static inline size_t align_up(size_t v, size_t a) { return (v + a - 1) & ~(a - 1); }

// ---------------------------------------------------------------------------
// K1: degree count + per-edge rank: rank[e] = deg[col[e]]++ (atomic return).
// The rank makes the later CSR fill atomic-free.
// ---------------------------------------------------------------------------
__global__ void k_degree_rank(const int* __restrict__ col, int* __restrict__ deg,
                              int* __restrict__ rank, int n_edges) {
    int i = blockIdx.x * blockDim.x + threadIdx.x;
    int stride = gridDim.x * blockDim.x;
    for (; i < n_edges; i += stride) {
        rank[i] = atomicAdd(&deg[col[i]], 1);  // rank store is coalesced
    }
}

// ---------------------------------------------------------------------------
// Scan pass 1: per-block partial sums of deg (1024 elems / block)
// ---------------------------------------------------------------------------
__global__ void k_scan_partial(const int* __restrict__ deg, int* __restrict__ bsum,
                               int n) {
    __shared__ int s[SCAN_TPB];
    int t = threadIdx.x;
    int base = blockIdx.x * SCAN_BLOCK + t * 4;
    int v = 0;
#pragma unroll
    for (int j = 0; j < 4; ++j) {
        int idx = base + j;
        if (idx < n) v += deg[idx];
    }
    s[t] = v;
    __syncthreads();
    for (int off = SCAN_TPB / 2; off > 0; off >>= 1) {
        if (t < off) s[t] += s[t + off];
        __syncthreads();
    }
    if (t == 0) bsum[blockIdx.x] = s[0];
}

// ---------------------------------------------------------------------------
// Scan pass 2: exclusive scan of block sums (single block, up to 1024 blocks)
// also writes row_start[n_nodes] = n_edges
// ---------------------------------------------------------------------------
__global__ void k_scan_blocksums(int* __restrict__ bsum, int nb,
                                 int* __restrict__ row_start, int n_nodes,
                                 int n_edges) {
    __shared__ int s[1024];
    int t = threadIdx.x;
    int v = (t < nb) ? bsum[t] : 0;
    s[t] = v;
    __syncthreads();
    for (int off = 1; off < 1024; off <<= 1) {
        int x = (t >= off) ? s[t - off] : 0;
        __syncthreads();
        s[t] += x;
        __syncthreads();
    }
    if (t < nb) bsum[t] = s[t] - v;  // exclusive
    if (t == 0) row_start[n_nodes] = n_edges;
}

// ---------------------------------------------------------------------------
// Scan pass 3: full exclusive scan -> row_start; also dis = rsqrt(deg) fused
// ---------------------------------------------------------------------------
__global__ void k_scan_final(const int* __restrict__ deg, const int* __restrict__ bsum,
                             int* __restrict__ row_start, float* __restrict__ dis,
                             int n) {
    __shared__ int s[SCAN_TPB];
    int t = threadIdx.x;
    int base = blockIdx.x * SCAN_BLOCK + t * 4;
    int v[4];
#pragma unroll
    for (int j = 0; j < 4; ++j) {
        int idx = base + j;
        v[j] = (idx < n) ? deg[idx] : 0;
    }
    int tsum = v[0] + v[1] + v[2] + v[3];
    s[t] = tsum;
    __syncthreads();
    for (int off = 1; off < SCAN_TPB; off <<= 1) {
        int x = (t >= off) ? s[t - off] : 0;
        __syncthreads();
        s[t] += x;
        __syncthreads();
    }
    int run = bsum[blockIdx.x] + (s[t] - tsum);  // global exclusive prefix
#pragma unroll
    for (int j = 0; j < 4; ++j) {
        int idx = base + j;
        if (idx < n) {
            row_start[idx] = run;
            dis[idx] = (v[j] > 0) ? rsqrtf((float)v[j]) : 0.0f;
            run += v[j];
        }
    }
}

// ---------------------------------------------------------------------------
// K3: h = (x @ W) * dis   (fp32; block stages 16 x-rows in LDS, wave=4 nodes,
//     lane = out column, W column in registers)
// ---------------------------------------------------------------------------
#define MM_NODES 16
__global__ void __launch_bounds__(256) k_matmul(
    const float* __restrict__ x, const float* __restrict__ W,
    const float* __restrict__ dis, float* __restrict__ h, int n_nodes) {
    __shared__ float xs[MM_NODES * IN_DIM];  // 8 KB
    const int lane = threadIdx.x & 63;
    const int wv = threadIdx.x >> 6;  // 0..3

    float w[IN_DIM];
#pragma unroll
    for (int k = 0; k < IN_DIM; ++k) w[k] = W[k * OUT_DIM + lane];

    int nchunks = (n_nodes + MM_NODES - 1) / MM_NODES;
    for (int ch = blockIdx.x; ch < nchunks; ch += gridDim.x) {
        int base = ch * MM_NODES;
        int nrows = min(MM_NODES, n_nodes - base);
        __syncthreads();  // protect xs from previous iteration's readers
        const float4* xg = (const float4*)(x + (size_t)base * IN_DIM);
        int nf4 = nrows * IN_DIM / 4;
        for (int i = threadIdx.x; i < nf4; i += 256) ((float4*)xs)[i] = xg[i];
        __syncthreads();
#pragma unroll
        for (int j = 0; j < 4; ++j) {
            int local = wv * 4 + j;
            int node = base + local;
            if (local < nrows) {
                const float4* xr = (const float4*)(xs + local * IN_DIM);
                float acc = 0.0f;
#pragma unroll
                for (int k4 = 0; k4 < IN_DIM / 4; ++k4) {
                    float4 xv = xr[k4];  // LDS broadcast read
                    acc = fmaf(xv.x, w[k4 * 4 + 0], acc);
                    acc = fmaf(xv.y, w[k4 * 4 + 1], acc);
                    acc = fmaf(xv.z, w[k4 * 4 + 2], acc);
                    acc = fmaf(xv.w, w[k4 * 4 + 3], acc);
                }
                h[(size_t)node * OUT_DIM + lane] = acc * dis[node];
            }
        }
    }
}

// ---------------------------------------------------------------------------
// K4: atomic-free CSR fill: edge_src[row_start[col[e]] + rank[e]] = row[e]
// ---------------------------------------------------------------------------
__global__ void k_fill2(const int* __restrict__ row, const int* __restrict__ col,
                        const int* __restrict__ row_start, const int* __restrict__ rank,
                        int* __restrict__ edge_src, int n_edges) {
    int i = blockIdx.x * blockDim.x + threadIdx.x;
    int stride = gridDim.x * blockDim.x;
    for (; i < n_edges; i += stride) {
        int c = col[i];                         // coalesced
        int pos = row_start[c] + rank[i];       // random 4B read (L2) + coalesced
        edge_src[pos] = row[i];                 // random 4B store, no RMW
    }
}

// ---------------------------------------------------------------------------
// K5: aggregation: out[c] = relu(dis[c] * sum_{r in N(c)} h[r] + b)
//     one wave per target node, lane = out column; unroll-4 gathers for ILP
// ---------------------------------------------------------------------------
__global__ void __launch_bounds__(256) k_aggregate(
    const int* __restrict__ row_start, const int* __restrict__ edge_src,
    const float* __restrict__ dis, const float* __restrict__ h,
    const float* __restrict__ b, float* __restrict__ out, int n_nodes) {
    const int lane = threadIdx.x & 63;
    int wid = (blockIdx.x * blockDim.x + threadIdx.x) >> 6;
    int nw = (gridDim.x * blockDim.x) >> 6;
    float bias = b[lane];
    for (int c = wid; c < n_nodes; c += nw) {
        int s = row_start[c];
        int e = row_start[c + 1];
        float a0 = 0.0f, a1 = 0.0f, a2 = 0.0f, a3 = 0.0f;
        int i = s;
        for (; i + 3 < e; i += 4) {  // 4 independent gathers in flight
            int r0 = edge_src[i];
            int r1 = edge_src[i + 1];
            int r2 = edge_src[i + 2];
            int r3 = edge_src[i + 3];
            a0 += h[(size_t)r0 * OUT_DIM + lane];
            a1 += h[(size_t)r1 * OUT_DIM + lane];
            a2 += h[(size_t)r2 * OUT_DIM + lane];
            a3 += h[(size_t)r3 * OUT_DIM + lane];
        }
        for (; i < e; ++i) a0 += h[(size_t)edge_src[i] * OUT_DIM + lane];
        float acc = (a0 + a1) + (a2 + a3);
        float v = fmaf(acc, dis[c], bias);
        out[(size_t)c * OUT_DIM + lane] = fmaxf(v, 0.0f);
    }
}

// ---------------------------------------------------------------------------
// Fallback path (if workspace too small for CSR): atomic scatter
// ---------------------------------------------------------------------------
__global__ void k_rsqrt_fb(const int* __restrict__ deg, float* __restrict__ dis, int n) {
    int i = blockIdx.x * blockDim.x + threadIdx.x;
    if (i < n) {
        int d = deg[i];
        dis[i] = (d > 0) ? rsqrtf((float)d) : 0.0f;
    }
}

__global__ void __launch_bounds__(256) k_scatter_fb(
    const int* __restrict__ row, const int* __restrict__ col,
    const float* __restrict__ dis, const float* __restrict__ h,
    float* __restrict__ out, int n_edges) {
    const int lane = threadIdx.x & 63;
    int e = (blockIdx.x * blockDim.x + threadIdx.x) >> 6;
    int nw = (gridDim.x * blockDim.x) >> 6;
    for (; e < n_edges; e += nw) {
        int r = row[e];
        int c = col[e];
        float v = h[(size_t)r * OUT_DIM + lane] * dis[c];  // h already has dis[r]
        atomicAdd(&out[(size_t)c * OUT_DIM + lane], v);
    }
}

__global__ void k_bias_relu_fb(float* __restrict__ out, const float* __restrict__ b,
                               int total) {
    int i = blockIdx.x * blockDim.x + threadIdx.x;
    int stride = gridDim.x * blockDim.x;
    for (; i < total; i += stride) {
        float v = out[i] + b[i & (OUT_DIM - 1)];
        out[i] = fmaxf(v, 0.0f);
    }
}

extern "C" void kernel_launch(void* const* d_in, const int* in_sizes, int n_in,
                              void* d_out, int out_size, void* d_ws, size_t ws_size,
                              hipStream_t stream) {
    const float* x = (const float*)d_in[0];
    const int* ei = (const int*)d_in[1];  // [2, E] int32
    const float* W = (const float*)d_in[2];
    const float* b = (const float*)d_in[3];
    float* out = (float*)d_out;

    const int n_nodes = in_sizes[0] / IN_DIM;
    const int n_edges = in_sizes[1] / 2;
    const int* row = ei;
    const int* col = ei + n_edges;

    // ---- workspace layout (CSR path) ----
    char* wsb = (char*)d_ws;
    size_t off = 0;
    int* deg = (int*)(wsb + off);       off += align_up((size_t)n_nodes * 4, 256);
    int* row_start = (int*)(wsb + off); off += align_up((size_t)(n_nodes + 1) * 4, 256);
    int* bsum = (int*)(wsb + off);      off += align_up(1024 * 4, 256);
    float* dis = (float*)(wsb + off);   off += align_up((size_t)n_nodes * 4, 256);
    int* rank = (int*)(wsb + off);      off += align_up((size_t)n_edges * 4, 256);
    int* edge_src = (int*)(wsb + off);  off += align_up((size_t)n_edges * 4, 256);
    float* h = (float*)(wsb + off);     off += (size_t)n_nodes * OUT_DIM * 4;
    const size_t needed = off;

    const int nb = (n_nodes + SCAN_BLOCK - 1) / SCAN_BLOCK;  // scan blocks (<=1024)

    if (ws_size >= needed && nb <= 1024) {
        // ---- CSR (atomic-free fill + aggregation) path ----
        hipMemsetAsync(deg, 0, (size_t)n_nodes * 4, stream);
        k_degree_rank<<<2048, 256, 0, stream>>>(col, deg, rank, n_edges);
        k_scan_partial<<<nb, SCAN_TPB, 0, stream>>>(deg, bsum, n_nodes);
        k_scan_blocksums<<<1, 1024, 0, stream>>>(bsum, nb, row_start, n_nodes, n_edges);
        k_scan_final<<<nb, SCAN_TPB, 0, stream>>>(deg, bsum, row_start, dis, n_nodes);
        k_matmul<<<1024, 256, 0, stream>>>(x, W, dis, h, n_nodes);
        k_fill2<<<2048, 256, 0, stream>>>(row, col, row_start, rank, edge_src, n_edges);
        int agg_blocks = (n_nodes + 3) / 4 / 64 + 1;  // ~4 nodes per wave
        k_aggregate<<<agg_blocks * 64, 256, 0, stream>>>(row_start, edge_src, dis, h, b,
                                                         out, n_nodes);
    } else {
        // ---- fallback: atomic scatter ----
        char* p = (char*)d_ws;
        int* deg_f = (int*)p;
        float* dis_f = (float*)(p + align_up((size_t)n_nodes * 4, 256));
        float* h_f = (float*)(p + 2 * align_up((size_t)n_nodes * 4, 256));
        int* rank_f = (int*)(p + 2 * align_up((size_t)n_nodes * 4, 256) +
                             (size_t)n_nodes * OUT_DIM * 4);
        hipMemsetAsync(deg_f, 0, (size_t)n_nodes * 4, stream);
        hipMemsetAsync(out, 0, (size_t)out_size * 4, stream);
        k_degree_rank<<<2048, 256, 0, stream>>>(col, deg_f, rank_f, n_edges);
        k_rsqrt_fb<<<(n_nodes + 255) / 256, 256, 0, stream>>>(deg_f, dis_f, n_nodes);
        k_matmul<<<1024, 256, 0, stream>>>(x, W, dis_f, h_f, n_nodes);
        k_scatter_fb<<<2048, 256, 0, stream>>>(row, col, dis_f, h_f, out, n_edges);
        k_bias_relu_fb<<<2048, 256, 0, stream>>>(out, b, n_nodes * OUT_DIM);
    }
}

// Round 4
// 258.388 us; speedup vs baseline: 3.1039x; 1.2714x over previous
//
#include <hip/hip_runtime.h>
#include <hip/hip_bf16.h>

#define IN_DIM 128
#define OUT_DIM 64
#define NPB_LOG 9                  // 512 nodes per bucket
#define NPB (1 << NPB_LOG)
#define MAXBUCK 1024               // supports n_nodes <= 512K
#define B1 1024                    // bucketing blocks (kA/kB); must match between them
#define SCAN_TPB 256

static inline size_t align_up(size_t v, size_t a) { return (v + a - 1) & ~(a - 1); }

// ---------------------------------------------------------------------------
// kA: per-block LDS histogram of col>>9 -> Hist[blk][bin]
// ---------------------------------------------------------------------------
__global__ void __launch_bounds__(256) kA_count(
    const int* __restrict__ col, int* __restrict__ Hist,
    int n_edges, int nbuck, int chunk) {
    __shared__ int hist[MAXBUCK];
    for (int i = threadIdx.x; i < nbuck; i += 256) hist[i] = 0;
    __syncthreads();
    int start = blockIdx.x * chunk;
    int end = min(n_edges, start + chunk);
    for (int i = start + threadIdx.x; i < end; i += 256)
        atomicAdd(&hist[col[i] >> NPB_LOG], 1);
    __syncthreads();
    int* hrow = Hist + (size_t)blockIdx.x * nbuck;
    for (int i = threadIdx.x; i < nbuck; i += 256) hrow[i] = hist[i];
}

// ---------------------------------------------------------------------------
// kS1: per-bin exclusive scan over blocks: Offs[blk][bin], BinTotal[bin]
// grid = nbuck blocks; B1=1024 values per bin, 4 per thread
// ---------------------------------------------------------------------------
__global__ void __launch_bounds__(256) kS1_scanbins(
    const int* __restrict__ Hist, int* __restrict__ Offs,
    int* __restrict__ BinTotal, int nbuck) {
    __shared__ int s[SCAN_TPB];
    int bin = blockIdx.x;
    int t = threadIdx.x;
    int v[4];
#pragma unroll
    for (int j = 0; j < 4; ++j) v[j] = Hist[(size_t)(t * 4 + j) * nbuck + bin];
    int tsum = v[0] + v[1] + v[2] + v[3];
    s[t] = tsum;
    __syncthreads();
    for (int off = 1; off < SCAN_TPB; off <<= 1) {
        int x = (t >= off) ? s[t - off] : 0;
        __syncthreads();
        s[t] += x;
        __syncthreads();
    }
    int run = s[t] - tsum;  // exclusive prefix
#pragma unroll
    for (int j = 0; j < 4; ++j) {
        Offs[(size_t)(t * 4 + j) * nbuck + bin] = run;
        run += v[j];
    }
    if (t == SCAN_TPB - 1) BinTotal[bin] = run;
}

// ---------------------------------------------------------------------------
// kS2: exclusive scan of BinTotal -> BucketStart[nbuck+1]; sentinels
// ---------------------------------------------------------------------------
__global__ void __launch_bounds__(256) kS2_scantotals(
    const int* __restrict__ BinTotal, int* __restrict__ BucketStart,
    int* __restrict__ row_start, int nbuck, int n_nodes, int n_edges) {
    __shared__ int s[SCAN_TPB];
    int t = threadIdx.x;
    int v[4];
#pragma unroll
    for (int j = 0; j < 4; ++j) {
        int idx = t * 4 + j;
        v[j] = (idx < nbuck) ? BinTotal[idx] : 0;
    }
    int tsum = v[0] + v[1] + v[2] + v[3];
    s[t] = tsum;
    __syncthreads();
    for (int off = 1; off < SCAN_TPB; off <<= 1) {
        int x = (t >= off) ? s[t - off] : 0;
        __syncthreads();
        s[t] += x;
        __syncthreads();
    }
    int run = s[t] - tsum;
#pragma unroll
    for (int j = 0; j < 4; ++j) {
        int idx = t * 4 + j;
        if (idx < nbuck) BucketStart[idx] = run;
        run += v[j];
    }
    if (t == 0) {
        BucketStart[nbuck] = n_edges;
        row_start[n_nodes] = n_edges;
    }
}

// ---------------------------------------------------------------------------
// kB: scatter edges to bucket regions, packed (row<<9)|(col&511); LDS cursors
// ---------------------------------------------------------------------------
__global__ void __launch_bounds__(256) kB_scatter(
    const int* __restrict__ row, const int* __restrict__ col,
    const int* __restrict__ BucketStart, const int* __restrict__ Offs,
    unsigned int* __restrict__ EdgeBuf, int n_edges, int nbuck, int chunk) {
    __shared__ int cur[MAXBUCK];
    const int* orow = Offs + (size_t)blockIdx.x * nbuck;
    for (int i = threadIdx.x; i < nbuck; i += 256)
        cur[i] = BucketStart[i] + orow[i];
    __syncthreads();
    int start = blockIdx.x * chunk;
    int end = min(n_edges, start + chunk);
    for (int i = start + threadIdx.x; i < end; i += 256) {
        int c = col[i];
        int r = row[i];
        int bin = c >> NPB_LOG;
        int p = atomicAdd(&cur[bin], 1);
        EdgeBuf[p] = ((unsigned int)r << NPB_LOG) | (unsigned int)(c & (NPB - 1));
    }
}

// ---------------------------------------------------------------------------
// kC: per-bucket in-LDS counting sort -> row_start, dis (fused rsqrt), edge_src
// grid = nbuck blocks
// ---------------------------------------------------------------------------
__global__ void __launch_bounds__(256) kC_localsort(
    const unsigned int* __restrict__ EdgeBuf, const int* __restrict__ BucketStart,
    int* __restrict__ row_start, float* __restrict__ dis,
    int* __restrict__ edge_src, int n_nodes) {
    __shared__ int cnt[NPB];
    __shared__ int cur[NPB];
    __shared__ int s[SCAN_TPB];
    int t = threadIdx.x;
    int nb0 = blockIdx.x << NPB_LOG;
    int nn = min(NPB, n_nodes - nb0);
    int es = BucketStart[blockIdx.x];
    int ee = BucketStart[blockIdx.x + 1];

    for (int i = t; i < NPB; i += 256) cnt[i] = 0;
    __syncthreads();
    for (int i = es + t; i < ee; i += 256)
        atomicAdd(&cnt[EdgeBuf[i] & (NPB - 1)], 1);
    __syncthreads();

    // exclusive scan of cnt[0..511]: 2 elems per thread
    int a = cnt[2 * t];
    int b = cnt[2 * t + 1];
    int tsum = a + b;
    s[t] = tsum;
    __syncthreads();
    for (int off = 1; off < SCAN_TPB; off <<= 1) {
        int x = (t >= off) ? s[t - off] : 0;
        __syncthreads();
        s[t] += x;
        __syncthreads();
    }
    int excl = s[t] - tsum;
    // write row_start + dis (coalesced over the bucket's nodes)
    if (2 * t < nn) {
        row_start[nb0 + 2 * t] = es + excl;
        dis[nb0 + 2 * t] = (a > 0) ? rsqrtf((float)a) : 0.0f;
    }
    if (2 * t + 1 < nn) {
        row_start[nb0 + 2 * t + 1] = es + excl + a;
        dis[nb0 + 2 * t + 1] = (b > 0) ? rsqrtf((float)b) : 0.0f;
    }
    cur[2 * t] = excl;
    cur[2 * t + 1] = excl + a;
    __syncthreads();

    // place edges (bucket region is L2-resident on this second read)
    for (int i = es + t; i < ee; i += 256) {
        unsigned int v = EdgeBuf[i];
        int cl = v & (NPB - 1);
        int r = (int)(v >> NPB_LOG);
        int p = atomicAdd(&cur[cl], 1);
        edge_src[es + p] = r;
    }
}

// ---------------------------------------------------------------------------
// k_matmul: h = (x @ W) * dis
// ---------------------------------------------------------------------------
#define MM_NODES 16
__global__ void __launch_bounds__(256) k_matmul(
    const float* __restrict__ x, const float* __restrict__ W,
    const float* __restrict__ dis, float* __restrict__ h, int n_nodes) {
    __shared__ float xs[MM_NODES * IN_DIM];  // 8 KB
    const int lane = threadIdx.x & 63;
    const int wv = threadIdx.x >> 6;

    float w[IN_DIM];
#pragma unroll
    for (int k = 0; k < IN_DIM; ++k) w[k] = W[k * OUT_DIM + lane];

    int nchunks = (n_nodes + MM_NODES - 1) / MM_NODES;
    for (int ch = blockIdx.x; ch < nchunks; ch += gridDim.x) {
        int base = ch * MM_NODES;
        int nrows = min(MM_NODES, n_nodes - base);
        __syncthreads();
        const float4* xg = (const float4*)(x + (size_t)base * IN_DIM);
        int nf4 = nrows * IN_DIM / 4;
        for (int i = threadIdx.x; i < nf4; i += 256) ((float4*)xs)[i] = xg[i];
        __syncthreads();
#pragma unroll
        for (int j = 0; j < 4; ++j) {
            int local = wv * 4 + j;
            int node = base + local;
            if (local < nrows) {
                const float4* xr = (const float4*)(xs + local * IN_DIM);
                float acc = 0.0f;
#pragma unroll
                for (int k4 = 0; k4 < IN_DIM / 4; ++k4) {
                    float4 xv = xr[k4];
                    acc = fmaf(xv.x, w[k4 * 4 + 0], acc);
                    acc = fmaf(xv.y, w[k4 * 4 + 1], acc);
                    acc = fmaf(xv.z, w[k4 * 4 + 2], acc);
                    acc = fmaf(xv.w, w[k4 * 4 + 3], acc);
                }
                h[(size_t)node * OUT_DIM + lane] = acc * dis[node];
            }
        }
    }
}

// ---------------------------------------------------------------------------
// k_aggregate: out[c] = relu(dis[c] * sum h[r] + b); wave per node
// ---------------------------------------------------------------------------
__global__ void __launch_bounds__(256) k_aggregate(
    const int* __restrict__ row_start, const int* __restrict__ edge_src,
    const float* __restrict__ dis, const float* __restrict__ h,
    const float* __restrict__ b, float* __restrict__ out, int n_nodes) {
    const int lane = threadIdx.x & 63;
    int wid = (blockIdx.x * blockDim.x + threadIdx.x) >> 6;
    int nw = (gridDim.x * blockDim.x) >> 6;
    float bias = b[lane];
    for (int c = wid; c < n_nodes; c += nw) {
        int s = row_start[c];
        int e = row_start[c + 1];
        float a0 = 0.0f, a1 = 0.0f, a2 = 0.0f, a3 = 0.0f;
        int i = s;
        for (; i + 3 < e; i += 4) {
            int r0 = edge_src[i];
            int r1 = edge_src[i + 1];
            int r2 = edge_src[i + 2];
            int r3 = edge_src[i + 3];
            a0 += h[(size_t)r0 * OUT_DIM + lane];
            a1 += h[(size_t)r1 * OUT_DIM + lane];
            a2 += h[(size_t)r2 * OUT_DIM + lane];
            a3 += h[(size_t)r3 * OUT_DIM + lane];
        }
        for (; i < e; ++i) a0 += h[(size_t)edge_src[i] * OUT_DIM + lane];
        float acc = (a0 + a1) + (a2 + a3);
        float v = fmaf(acc, dis[c], bias);
        out[(size_t)c * OUT_DIM + lane] = fmaxf(v, 0.0f);
    }
}

// ---------------------------------------------------------------------------
// Fallback path (exotic sizes / small workspace): atomic scatter
// ---------------------------------------------------------------------------
__global__ void k_degree_fb(const int* __restrict__ col, int* __restrict__ deg,
                            int n_edges) {
    int i = blockIdx.x * blockDim.x + threadIdx.x;
    int stride = gridDim.x * blockDim.x;
    for (; i < n_edges; i += stride) atomicAdd(&deg[col[i]], 1);
}

__global__ void k_rsqrt_fb(const int* __restrict__ deg, float* __restrict__ dis, int n) {
    int i = blockIdx.x * blockDim.x + threadIdx.x;
    if (i < n) {
        int d = deg[i];
        dis[i] = (d > 0) ? rsqrtf((float)d) : 0.0f;
    }
}

__global__ void __launch_bounds__(256) k_scatter_fb(
    const int* __restrict__ row, const int* __restrict__ col,
    const float* __restrict__ dis, const float* __restrict__ h,
    float* __restrict__ out, int n_edges) {
    const int lane = threadIdx.x & 63;
    int e = (blockIdx.x * blockDim.x + threadIdx.x) >> 6;
    int nw = (gridDim.x * blockDim.x) >> 6;
    for (; e < n_edges; e += nw) {
        int r = row[e];
        int c = col[e];
        float v = h[(size_t)r * OUT_DIM + lane] * dis[c];
        atomicAdd(&out[(size_t)c * OUT_DIM + lane], v);
    }
}

__global__ void k_bias_relu_fb(float* __restrict__ out, const float* __restrict__ b,
                               int total) {
    int i = blockIdx.x * blockDim.x + threadIdx.x;
    int stride = gridDim.x * blockDim.x;
    for (; i < total; i += stride) {
        float v = out[i] + b[i & (OUT_DIM - 1)];
        out[i] = fmaxf(v, 0.0f);
    }
}

extern "C" void kernel_launch(void* const* d_in, const int* in_sizes, int n_in,
                              void* d_out, int out_size, void* d_ws, size_t ws_size,
                              hipStream_t stream) {
    const float* x = (const float*)d_in[0];
    const int* ei = (const int*)d_in[1];  // [2, E] int32
    const float* W = (const float*)d_in[2];
    const float* b = (const float*)d_in[3];
    float* out = (float*)d_out;

    const int n_nodes = in_sizes[0] / IN_DIM;
    const int n_edges = in_sizes[1] / 2;
    const int* row = ei;
    const int* col = ei + n_edges;

    const int nbuck = (n_nodes + NPB - 1) >> NPB_LOG;
    const int chunk = (n_edges + B1 - 1) / B1;

    // ---- workspace layout ----
    char* wsb = (char*)d_ws;
    size_t off = 0;
    int* Hist = (int*)(wsb + off);       off += align_up((size_t)B1 * nbuck * 4, 256);
    int* Offs = (int*)(wsb + off);       off += align_up((size_t)B1 * nbuck * 4, 256);
    int* BinTotal = (int*)(wsb + off);   off += align_up((size_t)nbuck * 4, 256);
    int* BucketStart = (int*)(wsb + off);off += align_up((size_t)(nbuck + 1) * 4, 256);
    int* row_start = (int*)(wsb + off);  off += align_up((size_t)(n_nodes + 1) * 4, 256);
    float* dis = (float*)(wsb + off);    off += align_up((size_t)n_nodes * 4, 256);
    unsigned int* EdgeBuf = (unsigned int*)(wsb + off);
                                         off += align_up((size_t)n_edges * 4, 256);
    int* edge_src = (int*)(wsb + off);   off += align_up((size_t)n_edges * 4, 256);
    float* h = (float*)(wsb + off);      off += (size_t)n_nodes * OUT_DIM * 4;
    const size_t needed = off;

    const bool ok = (ws_size >= needed) && (nbuck <= MAXBUCK) &&
                    (n_nodes <= (1 << 23));

    if (ok) {
        kA_count<<<B1, 256, 0, stream>>>(col, Hist, n_edges, nbuck, chunk);
        kS1_scanbins<<<nbuck, 256, 0, stream>>>(Hist, Offs, BinTotal, nbuck);
        kS2_scantotals<<<1, 256, 0, stream>>>(BinTotal, BucketStart, row_start,
                                              nbuck, n_nodes, n_edges);
        kB_scatter<<<B1, 256, 0, stream>>>(row, col, BucketStart, Offs, EdgeBuf,
                                           n_edges, nbuck, chunk);
        kC_localsort<<<nbuck, 256, 0, stream>>>(EdgeBuf, BucketStart, row_start,
                                                dis, edge_src, n_nodes);
        k_matmul<<<1024, 256, 0, stream>>>(x, W, dis, h, n_nodes);
        int agg_blocks = (n_nodes + 3) / 4 / 64 + 1;
        k_aggregate<<<agg_blocks * 64, 256, 0, stream>>>(row_start, edge_src, dis,
                                                         h, b, out, n_nodes);
    } else {
        // ---- fallback: atomic scatter ----
        char* p = (char*)d_ws;
        int* deg_f = (int*)p;
        float* dis_f = (float*)(p + align_up((size_t)n_nodes * 4, 256));
        float* h_f = (float*)(p + 2 * align_up((size_t)n_nodes * 4, 256));
        hipMemsetAsync(deg_f, 0, (size_t)n_nodes * 4, stream);
        hipMemsetAsync(out, 0, (size_t)out_size * 4, stream);
        k_degree_fb<<<1024, 256, 0, stream>>>(col, deg_f, n_edges);
        k_rsqrt_fb<<<(n_nodes + 255) / 256, 256, 0, stream>>>(deg_f, dis_f, n_nodes);
        k_matmul<<<1024, 256, 0, stream>>>(x, W, dis_f, h_f, n_nodes);
        k_scatter_fb<<<2048, 256, 0, stream>>>(row, col, dis_f, h_f, out, n_edges);
        k_bias_relu_fb<<<2048, 256, 0, stream>>>(out, b, n_nodes * OUT_DIM);
    }
}

// Round 5
// 231.187 us; speedup vs baseline: 3.4691x; 1.1177x over previous
//
#include <hip/hip_runtime.h>
#include <hip/hip_bf16.h>

#define IN_DIM 128
#define OUT_DIM 64
#define NPB_LOG 9                  // 512 nodes per bucket
#define NPB (1 << NPB_LOG)
#define MAXBUCK 1024               // supports n_nodes <= 512K
#define B1 1024                    // bucketing blocks (kA/kB); must match between them
#define SCAN_TPB 256

static inline size_t align_up(size_t v, size_t a) { return (v + a - 1) & ~(a - 1); }

__device__ __forceinline__ float bf2f(unsigned short u) {
    return __uint_as_float(((unsigned int)u) << 16);
}
__device__ __forceinline__ unsigned short f2bf(float f) {
    unsigned int x = __float_as_uint(f);
    // round-to-nearest-even
    unsigned int r = (x + 0x7fffu + ((x >> 16) & 1u)) >> 16;
    return (unsigned short)r;
}

// ---------------------------------------------------------------------------
// kA: per-block LDS histogram of col>>9 -> Hist[blk][bin]
// ---------------------------------------------------------------------------
__global__ void __launch_bounds__(256) kA_count(
    const int* __restrict__ col, int* __restrict__ Hist,
    int n_edges, int nbuck, int chunk) {
    __shared__ int hist[MAXBUCK];
    for (int i = threadIdx.x; i < nbuck; i += 256) hist[i] = 0;
    __syncthreads();
    int start = blockIdx.x * chunk;
    int end = min(n_edges, start + chunk);
    for (int i = start + threadIdx.x; i < end; i += 256)
        atomicAdd(&hist[col[i] >> NPB_LOG], 1);
    __syncthreads();
    int* hrow = Hist + (size_t)blockIdx.x * nbuck;
    for (int i = threadIdx.x; i < nbuck; i += 256) hrow[i] = hist[i];
}

// ---------------------------------------------------------------------------
// kS1: per-bin exclusive scan over blocks: Offs[blk][bin], BinTotal[bin]
// ---------------------------------------------------------------------------
__global__ void __launch_bounds__(256) kS1_scanbins(
    const int* __restrict__ Hist, int* __restrict__ Offs,
    int* __restrict__ BinTotal, int nbuck) {
    __shared__ int s[SCAN_TPB];
    int bin = blockIdx.x;
    int t = threadIdx.x;
    int v[4];
#pragma unroll
    for (int j = 0; j < 4; ++j) v[j] = Hist[(size_t)(t * 4 + j) * nbuck + bin];
    int tsum = v[0] + v[1] + v[2] + v[3];
    s[t] = tsum;
    __syncthreads();
    for (int off = 1; off < SCAN_TPB; off <<= 1) {
        int x = (t >= off) ? s[t - off] : 0;
        __syncthreads();
        s[t] += x;
        __syncthreads();
    }
    int run = s[t] - tsum;  // exclusive prefix
#pragma unroll
    for (int j = 0; j < 4; ++j) {
        Offs[(size_t)(t * 4 + j) * nbuck + bin] = run;
        run += v[j];
    }
    if (t == SCAN_TPB - 1) BinTotal[bin] = run;
}

// ---------------------------------------------------------------------------
// kS2: exclusive scan of BinTotal -> BucketStart[nbuck+1]; sentinels
// ---------------------------------------------------------------------------
__global__ void __launch_bounds__(256) kS2_scantotals(
    const int* __restrict__ BinTotal, int* __restrict__ BucketStart,
    int* __restrict__ row_start, int nbuck, int n_nodes, int n_edges) {
    __shared__ int s[SCAN_TPB];
    int t = threadIdx.x;
    int v[4];
#pragma unroll
    for (int j = 0; j < 4; ++j) {
        int idx = t * 4 + j;
        v[j] = (idx < nbuck) ? BinTotal[idx] : 0;
    }
    int tsum = v[0] + v[1] + v[2] + v[3];
    s[t] = tsum;
    __syncthreads();
    for (int off = 1; off < SCAN_TPB; off <<= 1) {
        int x = (t >= off) ? s[t - off] : 0;
        __syncthreads();
        s[t] += x;
        __syncthreads();
    }
    int run = s[t] - tsum;
#pragma unroll
    for (int j = 0; j < 4; ++j) {
        int idx = t * 4 + j;
        if (idx < nbuck) BucketStart[idx] = run;
        run += v[j];
    }
    if (t == 0) {
        BucketStart[nbuck] = n_edges;
        row_start[n_nodes] = n_edges;
    }
}

// ---------------------------------------------------------------------------
// kB: scatter edges to bucket regions, packed (row<<9)|(col&511); LDS cursors
// ---------------------------------------------------------------------------
__global__ void __launch_bounds__(256) kB_scatter(
    const int* __restrict__ row, const int* __restrict__ col,
    const int* __restrict__ BucketStart, const int* __restrict__ Offs,
    unsigned int* __restrict__ EdgeBuf, int n_edges, int nbuck, int chunk) {
    __shared__ int cur[MAXBUCK];
    const int* orow = Offs + (size_t)blockIdx.x * nbuck;
    for (int i = threadIdx.x; i < nbuck; i += 256)
        cur[i] = BucketStart[i] + orow[i];
    __syncthreads();
    int start = blockIdx.x * chunk;
    int end = min(n_edges, start + chunk);
    for (int i = start + threadIdx.x; i < end; i += 256) {
        int c = col[i];
        int r = row[i];
        int bin = c >> NPB_LOG;
        int p = atomicAdd(&cur[bin], 1);
        EdgeBuf[p] = ((unsigned int)r << NPB_LOG) | (unsigned int)(c & (NPB - 1));
    }
}

// ---------------------------------------------------------------------------
// kC: per-bucket in-LDS counting sort -> row_start, dis (fused rsqrt), edge_src
// ---------------------------------------------------------------------------
__global__ void __launch_bounds__(256) kC_localsort(
    const unsigned int* __restrict__ EdgeBuf, const int* __restrict__ BucketStart,
    int* __restrict__ row_start, float* __restrict__ dis,
    int* __restrict__ edge_src, int n_nodes) {
    __shared__ int cnt[NPB];
    __shared__ int cur[NPB];
    __shared__ int s[SCAN_TPB];
    int t = threadIdx.x;
    int nb0 = blockIdx.x << NPB_LOG;
    int nn = min(NPB, n_nodes - nb0);
    int es = BucketStart[blockIdx.x];
    int ee = BucketStart[blockIdx.x + 1];

    for (int i = t; i < NPB; i += 256) cnt[i] = 0;
    __syncthreads();
    for (int i = es + t; i < ee; i += 256)
        atomicAdd(&cnt[EdgeBuf[i] & (NPB - 1)], 1);
    __syncthreads();

    int a = cnt[2 * t];
    int b = cnt[2 * t + 1];
    int tsum = a + b;
    s[t] = tsum;
    __syncthreads();
    for (int off = 1; off < SCAN_TPB; off <<= 1) {
        int x = (t >= off) ? s[t - off] : 0;
        __syncthreads();
        s[t] += x;
        __syncthreads();
    }
    int excl = s[t] - tsum;
    if (2 * t < nn) {
        row_start[nb0 + 2 * t] = es + excl;
        dis[nb0 + 2 * t] = (a > 0) ? rsqrtf((float)a) : 0.0f;
    }
    if (2 * t + 1 < nn) {
        row_start[nb0 + 2 * t + 1] = es + excl + a;
        dis[nb0 + 2 * t + 1] = (b > 0) ? rsqrtf((float)b) : 0.0f;
    }
    cur[2 * t] = excl;
    cur[2 * t + 1] = excl + a;
    __syncthreads();

    for (int i = es + t; i < ee; i += 256) {
        unsigned int v = EdgeBuf[i];
        int cl = v & (NPB - 1);
        int r = (int)(v >> NPB_LOG);
        int p = atomicAdd(&cur[cl], 1);
        edge_src[es + p] = r;
    }
}

// ---------------------------------------------------------------------------
// k_matmul_bf: h(bf16) = (x @ W) * dis
// ---------------------------------------------------------------------------
#define MM_NODES 16
__global__ void __launch_bounds__(256) k_matmul_bf(
    const float* __restrict__ x, const float* __restrict__ W,
    const float* __restrict__ dis, unsigned short* __restrict__ h, int n_nodes) {
    __shared__ float xs[MM_NODES * IN_DIM];  // 8 KB
    const int lane = threadIdx.x & 63;
    const int wv = threadIdx.x >> 6;

    float w[IN_DIM];
#pragma unroll
    for (int k = 0; k < IN_DIM; ++k) w[k] = W[k * OUT_DIM + lane];

    int nchunks = (n_nodes + MM_NODES - 1) / MM_NODES;
    for (int ch = blockIdx.x; ch < nchunks; ch += gridDim.x) {
        int base = ch * MM_NODES;
        int nrows = min(MM_NODES, n_nodes - base);
        __syncthreads();
        const float4* xg = (const float4*)(x + (size_t)base * IN_DIM);
        int nf4 = nrows * IN_DIM / 4;
        for (int i = threadIdx.x; i < nf4; i += 256) ((float4*)xs)[i] = xg[i];
        __syncthreads();
#pragma unroll
        for (int j = 0; j < 4; ++j) {
            int local = wv * 4 + j;
            int node = base + local;
            if (local < nrows) {
                const float4* xr = (const float4*)(xs + local * IN_DIM);
                float acc = 0.0f;
#pragma unroll
                for (int k4 = 0; k4 < IN_DIM / 4; ++k4) {
                    float4 xv = xr[k4];
                    acc = fmaf(xv.x, w[k4 * 4 + 0], acc);
                    acc = fmaf(xv.y, w[k4 * 4 + 1], acc);
                    acc = fmaf(xv.z, w[k4 * 4 + 2], acc);
                    acc = fmaf(xv.w, w[k4 * 4 + 3], acc);
                }
                h[(size_t)node * OUT_DIM + lane] = f2bf(acc * dis[node]);
            }
        }
    }
}

// ---------------------------------------------------------------------------
// k_aggregate: out[c] = relu(dis[c] * sum h[r] + b); wave per node.
// Coalesced adjacency prefetch (deg<=64 in one load) + __shfl broadcast, so
// only the h-gathers touch memory in the inner loop. h is bf16 (128 B/edge).
// ---------------------------------------------------------------------------
__global__ void __launch_bounds__(256) k_aggregate(
    const int* __restrict__ row_start, const int* __restrict__ edge_src,
    const float* __restrict__ dis, const unsigned short* __restrict__ h,
    const float* __restrict__ b, float* __restrict__ out,
    int n_nodes, int n_edges) {
    const int lane = threadIdx.x & 63;
    int wid = (blockIdx.x * blockDim.x + threadIdx.x) >> 6;
    int nw = (gridDim.x * blockDim.x) >> 6;
    float bias = b[lane];
    for (int c = wid; c < n_nodes; c += nw) {
        int s = row_start[c];
        int e = row_start[c + 1];
        float a0 = 0.0f, a1 = 0.0f, a2 = 0.0f, a3 = 0.0f;
        for (int base = s; base < e; base += 64) {
            int li = base + lane;
            int eidx = edge_src[(li < n_edges) ? li : (n_edges - 1)];  // coalesced
            int cnt = min(64, e - base);
            int j = 0;
            for (; j + 3 < cnt; j += 4) {
                int r0 = __shfl(eidx, j, 64);
                int r1 = __shfl(eidx, j + 1, 64);
                int r2 = __shfl(eidx, j + 2, 64);
                int r3 = __shfl(eidx, j + 3, 64);
                a0 += bf2f(h[(size_t)r0 * OUT_DIM + lane]);
                a1 += bf2f(h[(size_t)r1 * OUT_DIM + lane]);
                a2 += bf2f(h[(size_t)r2 * OUT_DIM + lane]);
                a3 += bf2f(h[(size_t)r3 * OUT_DIM + lane]);
            }
            for (; j < cnt; ++j) {
                int r = __shfl(eidx, j, 64);
                a0 += bf2f(h[(size_t)r * OUT_DIM + lane]);
            }
        }
        float acc = (a0 + a1) + (a2 + a3);
        float v = fmaf(acc, dis[c], bias);
        out[(size_t)c * OUT_DIM + lane] = fmaxf(v, 0.0f);
    }
}

// ---------------------------------------------------------------------------
// Fallback path (exotic sizes / small workspace): atomic scatter, fp32 h
// ---------------------------------------------------------------------------
__global__ void __launch_bounds__(256) k_matmul_f32(
    const float* __restrict__ x, const float* __restrict__ W,
    const float* __restrict__ dis, float* __restrict__ h, int n_nodes) {
    __shared__ float xs[MM_NODES * IN_DIM];
    const int lane = threadIdx.x & 63;
    const int wv = threadIdx.x >> 6;
    float w[IN_DIM];
#pragma unroll
    for (int k = 0; k < IN_DIM; ++k) w[k] = W[k * OUT_DIM + lane];
    int nchunks = (n_nodes + MM_NODES - 1) / MM_NODES;
    for (int ch = blockIdx.x; ch < nchunks; ch += gridDim.x) {
        int base = ch * MM_NODES;
        int nrows = min(MM_NODES, n_nodes - base);
        __syncthreads();
        const float4* xg = (const float4*)(x + (size_t)base * IN_DIM);
        int nf4 = nrows * IN_DIM / 4;
        for (int i = threadIdx.x; i < nf4; i += 256) ((float4*)xs)[i] = xg[i];
        __syncthreads();
#pragma unroll
        for (int j = 0; j < 4; ++j) {
            int local = wv * 4 + j;
            int node = base + local;
            if (local < nrows) {
                const float4* xr = (const float4*)(xs + local * IN_DIM);
                float acc = 0.0f;
#pragma unroll
                for (int k4 = 0; k4 < IN_DIM / 4; ++k4) {
                    float4 xv = xr[k4];
                    acc = fmaf(xv.x, w[k4 * 4 + 0], acc);
                    acc = fmaf(xv.y, w[k4 * 4 + 1], acc);
                    acc = fmaf(xv.z, w[k4 * 4 + 2], acc);
                    acc = fmaf(xv.w, w[k4 * 4 + 3], acc);
                }
                h[(size_t)node * OUT_DIM + lane] = acc * dis[node];
            }
        }
    }
}

__global__ void k_degree_fb(const int* __restrict__ col, int* __restrict__ deg,
                            int n_edges) {
    int i = blockIdx.x * blockDim.x + threadIdx.x;
    int stride = gridDim.x * blockDim.x;
    for (; i < n_edges; i += stride) atomicAdd(&deg[col[i]], 1);
}

__global__ void k_rsqrt_fb(const int* __restrict__ deg, float* __restrict__ dis, int n) {
    int i = blockIdx.x * blockDim.x + threadIdx.x;
    if (i < n) {
        int d = deg[i];
        dis[i] = (d > 0) ? rsqrtf((float)d) : 0.0f;
    }
}

__global__ void __launch_bounds__(256) k_scatter_fb(
    const int* __restrict__ row, const int* __restrict__ col,
    const float* __restrict__ dis, const float* __restrict__ h,
    float* __restrict__ out, int n_edges) {
    const int lane = threadIdx.x & 63;
    int e = (blockIdx.x * blockDim.x + threadIdx.x) >> 6;
    int nw = (gridDim.x * blockDim.x) >> 6;
    for (; e < n_edges; e += nw) {
        int r = row[e];
        int c = col[e];
        float v = h[(size_t)r * OUT_DIM + lane] * dis[c];
        atomicAdd(&out[(size_t)c * OUT_DIM + lane], v);
    }
}

__global__ void k_bias_relu_fb(float* __restrict__ out, const float* __restrict__ b,
                               int total) {
    int i = blockIdx.x * blockDim.x + threadIdx.x;
    int stride = gridDim.x * blockDim.x;
    for (; i < total; i += stride) {
        float v = out[i] + b[i & (OUT_DIM - 1)];
        out[i] = fmaxf(v, 0.0f);
    }
}

extern "C" void kernel_launch(void* const* d_in, const int* in_sizes, int n_in,
                              void* d_out, int out_size, void* d_ws, size_t ws_size,
                              hipStream_t stream) {
    const float* x = (const float*)d_in[0];
    const int* ei = (const int*)d_in[1];  // [2, E] int32
    const float* W = (const float*)d_in[2];
    const float* b = (const float*)d_in[3];
    float* out = (float*)d_out;

    const int n_nodes = in_sizes[0] / IN_DIM;
    const int n_edges = in_sizes[1] / 2;
    const int* row = ei;
    const int* col = ei + n_edges;

    const int nbuck = (n_nodes + NPB - 1) >> NPB_LOG;
    const int chunk = (n_edges + B1 - 1) / B1;

    // ---- workspace layout ----
    char* wsb = (char*)d_ws;
    size_t off = 0;
    int* Hist = (int*)(wsb + off);       off += align_up((size_t)B1 * nbuck * 4, 256);
    int* Offs = (int*)(wsb + off);       off += align_up((size_t)B1 * nbuck * 4, 256);
    int* BinTotal = (int*)(wsb + off);   off += align_up((size_t)nbuck * 4, 256);
    int* BucketStart = (int*)(wsb + off);off += align_up((size_t)(nbuck + 1) * 4, 256);
    int* row_start = (int*)(wsb + off);  off += align_up((size_t)(n_nodes + 1) * 4, 256);
    float* dis = (float*)(wsb + off);    off += align_up((size_t)n_nodes * 4, 256);
    unsigned int* EdgeBuf = (unsigned int*)(wsb + off);
                                         off += align_up((size_t)n_edges * 4, 256);
    int* edge_src = (int*)(wsb + off);   off += align_up((size_t)n_edges * 4, 256);
    unsigned short* h = (unsigned short*)(wsb + off);
                                         off += (size_t)n_nodes * OUT_DIM * 2;
    const size_t needed = off;

    const bool ok = (ws_size >= needed) && (nbuck <= MAXBUCK) &&
                    (n_nodes <= (1 << 23));

    if (ok) {
        kA_count<<<B1, 256, 0, stream>>>(col, Hist, n_edges, nbuck, chunk);
        kS1_scanbins<<<nbuck, 256, 0, stream>>>(Hist, Offs, BinTotal, nbuck);
        kS2_scantotals<<<1, 256, 0, stream>>>(BinTotal, BucketStart, row_start,
                                              nbuck, n_nodes, n_edges);
        kB_scatter<<<B1, 256, 0, stream>>>(row, col, BucketStart, Offs, EdgeBuf,
                                           n_edges, nbuck, chunk);
        kC_localsort<<<nbuck, 256, 0, stream>>>(EdgeBuf, BucketStart, row_start,
                                                dis, edge_src, n_nodes);
        k_matmul_bf<<<1024, 256, 0, stream>>>(x, W, dis, h, n_nodes);
        int agg_blocks = (n_nodes + 3) / 4 + 1;  // one wave per node
        k_aggregate<<<agg_blocks, 256, 0, stream>>>(row_start, edge_src, dis, h, b,
                                                    out, n_nodes, n_edges);
    } else {
        // ---- fallback: atomic scatter, fp32 h ----
        char* p = (char*)d_ws;
        int* deg_f = (int*)p;
        float* dis_f = (float*)(p + align_up((size_t)n_nodes * 4, 256));
        float* h_f = (float*)(p + 2 * align_up((size_t)n_nodes * 4, 256));
        hipMemsetAsync(deg_f, 0, (size_t)n_nodes * 4, stream);
        hipMemsetAsync(out, 0, (size_t)out_size * 4, stream);
        k_degree_fb<<<1024, 256, 0, stream>>>(col, deg_f, n_edges);
        k_rsqrt_fb<<<(n_nodes + 255) / 256, 256, 0, stream>>>(deg_f, dis_f, n_nodes);
        k_matmul_f32<<<1024, 256, 0, stream>>>(x, W, dis_f, h_f, n_nodes);
        k_scatter_fb<<<2048, 256, 0, stream>>>(row, col, dis_f, h_f, out, n_edges);
        k_bias_relu_fb<<<2048, 256, 0, stream>>>(out, b, n_nodes * OUT_DIM);
    }
}

// Round 6
// 210.186 us; speedup vs baseline: 3.8157x; 1.0999x over previous
//
#include <hip/hip_runtime.h>
#include <hip/hip_bf16.h>

#define IN_DIM 128
#define OUT_DIM 64
#define NPB_LOG 9                  // 512 nodes per bucket
#define NPB (1 << NPB_LOG)
#define MAXBUCK 1024               // supports n_nodes <= 512K
#define B1 1024                    // bucketing blocks (kA/kB); must match between them
#define SCAN_TPB 256

static inline size_t align_up(size_t v, size_t a) { return (v + a - 1) & ~(a - 1); }

__device__ __forceinline__ float bf2f(unsigned short u) {
    return __uint_as_float(((unsigned int)u) << 16);
}
__device__ __forceinline__ unsigned short f2bf(float f) {
    unsigned int x = __float_as_uint(f);
    unsigned int r = (x + 0x7fffu + ((x >> 16) & 1u)) >> 16;  // RTNE
    return (unsigned short)r;
}

typedef _Float16 half8 __attribute__((ext_vector_type(8)));
typedef float f32x4 __attribute__((ext_vector_type(4)));

// ---------------------------------------------------------------------------
// kA: per-block LDS histogram of col>>9 -> Hist[blk][bin]
// ---------------------------------------------------------------------------
__global__ void __launch_bounds__(256) kA_count(
    const int* __restrict__ col, int* __restrict__ Hist,
    int n_edges, int nbuck, int chunk) {
    __shared__ int hist[MAXBUCK];
    for (int i = threadIdx.x; i < nbuck; i += 256) hist[i] = 0;
    __syncthreads();
    int start = blockIdx.x * chunk;
    int end = min(n_edges, start + chunk);
    for (int i = start + threadIdx.x; i < end; i += 256)
        atomicAdd(&hist[col[i] >> NPB_LOG], 1);
    __syncthreads();
    int* hrow = Hist + (size_t)blockIdx.x * nbuck;
    for (int i = threadIdx.x; i < nbuck; i += 256) hrow[i] = hist[i];
}

// ---------------------------------------------------------------------------
// kS1: per-bin exclusive scan over blocks: Offs[blk][bin], BinTotal[bin]
// ---------------------------------------------------------------------------
__global__ void __launch_bounds__(256) kS1_scanbins(
    const int* __restrict__ Hist, int* __restrict__ Offs,
    int* __restrict__ BinTotal, int nbuck) {
    __shared__ int s[SCAN_TPB];
    int bin = blockIdx.x;
    int t = threadIdx.x;
    int v[4];
#pragma unroll
    for (int j = 0; j < 4; ++j) v[j] = Hist[(size_t)(t * 4 + j) * nbuck + bin];
    int tsum = v[0] + v[1] + v[2] + v[3];
    s[t] = tsum;
    __syncthreads();
    for (int off = 1; off < SCAN_TPB; off <<= 1) {
        int x = (t >= off) ? s[t - off] : 0;
        __syncthreads();
        s[t] += x;
        __syncthreads();
    }
    int run = s[t] - tsum;  // exclusive prefix
#pragma unroll
    for (int j = 0; j < 4; ++j) {
        Offs[(size_t)(t * 4 + j) * nbuck + bin] = run;
        run += v[j];
    }
    if (t == SCAN_TPB - 1) BinTotal[bin] = run;
}

// ---------------------------------------------------------------------------
// kS2: exclusive scan of BinTotal -> BucketStart[nbuck+1]; sentinels
// ---------------------------------------------------------------------------
__global__ void __launch_bounds__(256) kS2_scantotals(
    const int* __restrict__ BinTotal, int* __restrict__ BucketStart,
    int* __restrict__ row_start, int nbuck, int n_nodes, int n_edges) {
    __shared__ int s[SCAN_TPB];
    int t = threadIdx.x;
    int v[4];
#pragma unroll
    for (int j = 0; j < 4; ++j) {
        int idx = t * 4 + j;
        v[j] = (idx < nbuck) ? BinTotal[idx] : 0;
    }
    int tsum = v[0] + v[1] + v[2] + v[3];
    s[t] = tsum;
    __syncthreads();
    for (int off = 1; off < SCAN_TPB; off <<= 1) {
        int x = (t >= off) ? s[t - off] : 0;
        __syncthreads();
        s[t] += x;
        __syncthreads();
    }
    int run = s[t] - tsum;
#pragma unroll
    for (int j = 0; j < 4; ++j) {
        int idx = t * 4 + j;
        if (idx < nbuck) BucketStart[idx] = run;
        run += v[j];
    }
    if (t == 0) {
        BucketStart[nbuck] = n_edges;
        row_start[n_nodes] = n_edges;
    }
}

// ---------------------------------------------------------------------------
// kB: scatter edges to bucket regions, packed (row<<9)|(col&511); LDS cursors
// ---------------------------------------------------------------------------
__global__ void __launch_bounds__(256) kB_scatter(
    const int* __restrict__ row, const int* __restrict__ col,
    const int* __restrict__ BucketStart, const int* __restrict__ Offs,
    unsigned int* __restrict__ EdgeBuf, int n_edges, int nbuck, int chunk) {
    __shared__ int cur[MAXBUCK];
    const int* orow = Offs + (size_t)blockIdx.x * nbuck;
    for (int i = threadIdx.x; i < nbuck; i += 256)
        cur[i] = BucketStart[i] + orow[i];
    __syncthreads();
    int start = blockIdx.x * chunk;
    int end = min(n_edges, start + chunk);
    for (int i = start + threadIdx.x; i < end; i += 256) {
        int c = col[i];
        int r = row[i];
        int bin = c >> NPB_LOG;
        int p = atomicAdd(&cur[bin], 1);
        EdgeBuf[p] = ((unsigned int)r << NPB_LOG) | (unsigned int)(c & (NPB - 1));
    }
}

// ---------------------------------------------------------------------------
// kC: per-bucket in-LDS counting sort -> row_start, dis (fused rsqrt), edge_src
// ---------------------------------------------------------------------------
__global__ void __launch_bounds__(256) kC_localsort(
    const unsigned int* __restrict__ EdgeBuf, const int* __restrict__ BucketStart,
    int* __restrict__ row_start, float* __restrict__ dis,
    int* __restrict__ edge_src, int n_nodes) {
    __shared__ int cnt[NPB];
    __shared__ int cur[NPB];
    __shared__ int s[SCAN_TPB];
    int t = threadIdx.x;
    int nb0 = blockIdx.x << NPB_LOG;
    int nn = min(NPB, n_nodes - nb0);
    int es = BucketStart[blockIdx.x];
    int ee = BucketStart[blockIdx.x + 1];

    for (int i = t; i < NPB; i += 256) cnt[i] = 0;
    __syncthreads();
    for (int i = es + t; i < ee; i += 256)
        atomicAdd(&cnt[EdgeBuf[i] & (NPB - 1)], 1);
    __syncthreads();

    int a = cnt[2 * t];
    int b = cnt[2 * t + 1];
    int tsum = a + b;
    s[t] = tsum;
    __syncthreads();
    for (int off = 1; off < SCAN_TPB; off <<= 1) {
        int x = (t >= off) ? s[t - off] : 0;
        __syncthreads();
        s[t] += x;
        __syncthreads();
    }
    int excl = s[t] - tsum;
    if (2 * t < nn) {
        row_start[nb0 + 2 * t] = es + excl;
        dis[nb0 + 2 * t] = (a > 0) ? rsqrtf((float)a) : 0.0f;
    }
    if (2 * t + 1 < nn) {
        row_start[nb0 + 2 * t + 1] = es + excl + a;
        dis[nb0 + 2 * t + 1] = (b > 0) ? rsqrtf((float)b) : 0.0f;
    }
    cur[2 * t] = excl;
    cur[2 * t + 1] = excl + a;
    __syncthreads();

    for (int i = es + t; i < ee; i += 256) {
        unsigned int v = EdgeBuf[i];
        int cl = v & (NPB - 1);
        int r = (int)(v >> NPB_LOG);
        int p = atomicAdd(&cur[cl], 1);
        edge_src[es + p] = r;
    }
}

// ---------------------------------------------------------------------------
// k_matmul_mfma: h(bf16) = (x @ W) * dis via f16 MFMA 16x16x32.
// One wave per 16-node tile. All 16 W-fragments (4 kt x 4 nt) hoisted into
// VGPRs once; A-frags loaded per-lane from global x (L1 absorbs the stride).
// No LDS, no barriers. Layouts (HW-verified, dtype-independent):
//   A[m=lane&15][k=(lane>>4)*8+j], B[n=lane&15][k=(lane>>4)*8+j],
//   D: col=lane&15, row=(lane>>4)*4+reg.
// ---------------------------------------------------------------------------
__global__ void __launch_bounds__(256) k_matmul_mfma(
    const float* __restrict__ x, const float* __restrict__ W,
    const float* __restrict__ dis, unsigned short* __restrict__ h, int n_nodes) {
    const int lane = threadIdx.x & 63;
    const int m = lane & 15;       // A-row / D-col index
    const int q = lane >> 4;       // quad
    const int wid = (blockIdx.x * blockDim.x + threadIdx.x) >> 6;
    const int ntiles = (n_nodes + 15) >> 4;
    if (wid >= ntiles) return;

    // ---- hoist all W fragments: bfrag[kt][nt], B[n=m][k=kt*32+q*8+j] ----
    half8 bfrag[4][4];
#pragma unroll
    for (int kt = 0; kt < 4; ++kt) {
#pragma unroll
        for (int nt = 0; nt < 4; ++nt) {
            int k0 = kt * 32 + q * 8;
            int c = nt * 16 + m;
#pragma unroll
            for (int j = 0; j < 8; ++j)
                bfrag[kt][nt][j] = (_Float16)W[(size_t)(k0 + j) * OUT_DIM + c];
        }
    }

    const int nb = wid << 4;  // tile's first node
    int arow = nb + m;
    if (arow >= n_nodes) arow = n_nodes - 1;  // clamp (loads only)
    const float* xr = x + (size_t)arow * IN_DIM;

    f32x4 acc[4];
#pragma unroll
    for (int nt = 0; nt < 4; ++nt) acc[nt] = (f32x4){0.f, 0.f, 0.f, 0.f};

#pragma unroll
    for (int kt = 0; kt < 4; ++kt) {
        const float4* xp = (const float4*)(xr + kt * 32 + q * 8);
        float4 lo = xp[0];
        float4 hi = xp[1];
        half8 afrag;
        afrag[0] = (_Float16)lo.x; afrag[1] = (_Float16)lo.y;
        afrag[2] = (_Float16)lo.z; afrag[3] = (_Float16)lo.w;
        afrag[4] = (_Float16)hi.x; afrag[5] = (_Float16)hi.y;
        afrag[6] = (_Float16)hi.z; afrag[7] = (_Float16)hi.w;
#pragma unroll
        for (int nt = 0; nt < 4; ++nt)
            acc[nt] = __builtin_amdgcn_mfma_f32_16x16x32_f16(afrag, bfrag[kt][nt],
                                                             acc[nt], 0, 0, 0);
    }

    // ---- epilogue: scale by dis[node], store bf16 h ----
#pragma unroll
    for (int r = 0; r < 4; ++r) {
        int node = nb + q * 4 + r;
        if (node < n_nodes) {
            float dv = dis[node];
            unsigned short* hp = h + (size_t)node * OUT_DIM + m;
#pragma unroll
            for (int nt = 0; nt < 4; ++nt)
                hp[nt * 16] = f2bf(acc[nt][r] * dv);
        }
    }
}

// ---------------------------------------------------------------------------
// k_aggregate: out[c] = relu(dis[c] * sum h[r] + b); wave per node.
// Coalesced adjacency prefetch + __shfl broadcast; h is bf16 (128 B/edge).
// ---------------------------------------------------------------------------
__global__ void __launch_bounds__(256) k_aggregate(
    const int* __restrict__ row_start, const int* __restrict__ edge_src,
    const float* __restrict__ dis, const unsigned short* __restrict__ h,
    const float* __restrict__ b, float* __restrict__ out,
    int n_nodes, int n_edges) {
    const int lane = threadIdx.x & 63;
    int wid = (blockIdx.x * blockDim.x + threadIdx.x) >> 6;
    int nw = (gridDim.x * blockDim.x) >> 6;
    float bias = b[lane];
    for (int c = wid; c < n_nodes; c += nw) {
        int s = row_start[c];
        int e = row_start[c + 1];
        float a0 = 0.0f, a1 = 0.0f, a2 = 0.0f, a3 = 0.0f;
        for (int base = s; base < e; base += 64) {
            int li = base + lane;
            int eidx = edge_src[(li < n_edges) ? li : (n_edges - 1)];  // coalesced
            int cnt = min(64, e - base);
            int j = 0;
            for (; j + 3 < cnt; j += 4) {
                int r0 = __shfl(eidx, j, 64);
                int r1 = __shfl(eidx, j + 1, 64);
                int r2 = __shfl(eidx, j + 2, 64);
                int r3 = __shfl(eidx, j + 3, 64);
                a0 += bf2f(h[(size_t)r0 * OUT_DIM + lane]);
                a1 += bf2f(h[(size_t)r1 * OUT_DIM + lane]);
                a2 += bf2f(h[(size_t)r2 * OUT_DIM + lane]);
                a3 += bf2f(h[(size_t)r3 * OUT_DIM + lane]);
            }
            for (; j < cnt; ++j) {
                int r = __shfl(eidx, j, 64);
                a0 += bf2f(h[(size_t)r * OUT_DIM + lane]);
            }
        }
        float acc = (a0 + a1) + (a2 + a3);
        float v = fmaf(acc, dis[c], bias);
        out[(size_t)c * OUT_DIM + lane] = fmaxf(v, 0.0f);
    }
}

// ---------------------------------------------------------------------------
// Fallback path (exotic sizes / small workspace): atomic scatter, fp32 h
// ---------------------------------------------------------------------------
#define MM_NODES 16
__global__ void __launch_bounds__(256) k_matmul_f32(
    const float* __restrict__ x, const float* __restrict__ W,
    const float* __restrict__ dis, float* __restrict__ h, int n_nodes) {
    __shared__ float xs[MM_NODES * IN_DIM];
    const int lane = threadIdx.x & 63;
    const int wv = threadIdx.x >> 6;
    float w[IN_DIM];
#pragma unroll
    for (int k = 0; k < IN_DIM; ++k) w[k] = W[k * OUT_DIM + lane];
    int nchunks = (n_nodes + MM_NODES - 1) / MM_NODES;
    for (int ch = blockIdx.x; ch < nchunks; ch += gridDim.x) {
        int base = ch * MM_NODES;
        int nrows = min(MM_NODES, n_nodes - base);
        __syncthreads();
        const float4* xg = (const float4*)(x + (size_t)base * IN_DIM);
        int nf4 = nrows * IN_DIM / 4;
        for (int i = threadIdx.x; i < nf4; i += 256) ((float4*)xs)[i] = xg[i];
        __syncthreads();
#pragma unroll
        for (int j = 0; j < 4; ++j) {
            int local = wv * 4 + j;
            int node = base + local;
            if (local < nrows) {
                const float4* xr = (const float4*)(xs + local * IN_DIM);
                float acc = 0.0f;
#pragma unroll
                for (int k4 = 0; k4 < IN_DIM / 4; ++k4) {
                    float4 xv = xr[k4];
                    acc = fmaf(xv.x, w[k4 * 4 + 0], acc);
                    acc = fmaf(xv.y, w[k4 * 4 + 1], acc);
                    acc = fmaf(xv.z, w[k4 * 4 + 2], acc);
                    acc = fmaf(xv.w, w[k4 * 4 + 3], acc);
                }
                h[(size_t)node * OUT_DIM + lane] = acc * dis[node];
            }
        }
    }
}

__global__ void k_degree_fb(const int* __restrict__ col, int* __restrict__ deg,
                            int n_edges) {
    int i = blockIdx.x * blockDim.x + threadIdx.x;
    int stride = gridDim.x * blockDim.x;
    for (; i < n_edges; i += stride) atomicAdd(&deg[col[i]], 1);
}

__global__ void k_rsqrt_fb(const int* __restrict__ deg, float* __restrict__ dis, int n) {
    int i = blockIdx.x * blockDim.x + threadIdx.x;
    if (i < n) {
        int d = deg[i];
        dis[i] = (d > 0) ? rsqrtf((float)d) : 0.0f;
    }
}

__global__ void __launch_bounds__(256) k_scatter_fb(
    const int* __restrict__ row, const int* __restrict__ col,
    const float* __restrict__ dis, const float* __restrict__ h,
    float* __restrict__ out, int n_edges) {
    const int lane = threadIdx.x & 63;
    int e = (blockIdx.x * blockDim.x + threadIdx.x) >> 6;
    int nw = (gridDim.x * blockDim.x) >> 6;
    for (; e < n_edges; e += nw) {
        int r = row[e];
        int c = col[e];
        float v = h[(size_t)r * OUT_DIM + lane] * dis[c];
        atomicAdd(&out[(size_t)c * OUT_DIM + lane], v);
    }
}

__global__ void k_bias_relu_fb(float* __restrict__ out, const float* __restrict__ b,
                               int total) {
    int i = blockIdx.x * blockDim.x + threadIdx.x;
    int stride = gridDim.x * blockDim.x;
    for (; i < total; i += stride) {
        float v = out[i] + b[i & (OUT_DIM - 1)];
        out[i] = fmaxf(v, 0.0f);
    }
}

extern "C" void kernel_launch(void* const* d_in, const int* in_sizes, int n_in,
                              void* d_out, int out_size, void* d_ws, size_t ws_size,
                              hipStream_t stream) {
    const float* x = (const float*)d_in[0];
    const int* ei = (const int*)d_in[1];  // [2, E] int32
    const float* W = (const float*)d_in[2];
    const float* b = (const float*)d_in[3];
    float* out = (float*)d_out;

    const int n_nodes = in_sizes[0] / IN_DIM;
    const int n_edges = in_sizes[1] / 2;
    const int* row = ei;
    const int* col = ei + n_edges;

    const int nbuck = (n_nodes + NPB - 1) >> NPB_LOG;
    const int chunk = (n_edges + B1 - 1) / B1;

    // ---- workspace layout ----
    char* wsb = (char*)d_ws;
    size_t off = 0;
    int* Hist = (int*)(wsb + off);       off += align_up((size_t)B1 * nbuck * 4, 256);
    int* Offs = (int*)(wsb + off);       off += align_up((size_t)B1 * nbuck * 4, 256);
    int* BinTotal = (int*)(wsb + off);   off += align_up((size_t)nbuck * 4, 256);
    int* BucketStart = (int*)(wsb + off);off += align_up((size_t)(nbuck + 1) * 4, 256);
    int* row_start = (int*)(wsb + off);  off += align_up((size_t)(n_nodes + 1) * 4, 256);
    float* dis = (float*)(wsb + off);    off += align_up((size_t)n_nodes * 4, 256);
    unsigned int* EdgeBuf = (unsigned int*)(wsb + off);
                                         off += align_up((size_t)n_edges * 4, 256);
    int* edge_src = (int*)(wsb + off);   off += align_up((size_t)n_edges * 4, 256);
    unsigned short* h = (unsigned short*)(wsb + off);
                                         off += (size_t)n_nodes * OUT_DIM * 2;
    const size_t needed = off;

    const bool ok = (ws_size >= needed) && (nbuck <= MAXBUCK) &&
                    (n_nodes <= (1 << 23));

    if (ok) {
        kA_count<<<B1, 256, 0, stream>>>(col, Hist, n_edges, nbuck, chunk);
        kS1_scanbins<<<nbuck, 256, 0, stream>>>(Hist, Offs, BinTotal, nbuck);
        kS2_scantotals<<<1, 256, 0, stream>>>(BinTotal, BucketStart, row_start,
                                              nbuck, n_nodes, n_edges);
        kB_scatter<<<B1, 256, 0, stream>>>(row, col, BucketStart, Offs, EdgeBuf,
                                           n_edges, nbuck, chunk);
        kC_localsort<<<nbuck, 256, 0, stream>>>(EdgeBuf, BucketStart, row_start,
                                                dis, edge_src, n_nodes);
        int ntiles = (n_nodes + 15) / 16;           // one wave per 16 nodes
        int mm_blocks = (ntiles + 3) / 4;           // 4 waves per block
        k_matmul_mfma<<<mm_blocks, 256, 0, stream>>>(x, W, dis, h, n_nodes);
        int agg_blocks = (n_nodes + 3) / 4 + 1;     // one wave per node
        k_aggregate<<<agg_blocks, 256, 0, stream>>>(row_start, edge_src, dis, h, b,
                                                    out, n_nodes, n_edges);
    } else {
        // ---- fallback: atomic scatter, fp32 h ----
        char* p = (char*)d_ws;
        int* deg_f = (int*)p;
        float* dis_f = (float*)(p + align_up((size_t)n_nodes * 4, 256));
        float* h_f = (float*)(p + 2 * align_up((size_t)n_nodes * 4, 256));
        hipMemsetAsync(deg_f, 0, (size_t)n_nodes * 4, stream);
        hipMemsetAsync(out, 0, (size_t)out_size * 4, stream);
        k_degree_fb<<<1024, 256, 0, stream>>>(col, deg_f, n_edges);
        k_rsqrt_fb<<<(n_nodes + 255) / 256, 256, 0, stream>>>(deg_f, dis_f, n_nodes);
        k_matmul_f32<<<1024, 256, 0, stream>>>(x, W, dis_f, h_f, n_nodes);
        k_scatter_fb<<<2048, 256, 0, stream>>>(row, col, dis_f, h_f, out, n_edges);
        k_bias_relu_fb<<<2048, 256, 0, stream>>>(out, b, n_nodes * OUT_DIM);
    }
}

// Round 8
// 199.723 us; speedup vs baseline: 4.0156x; 1.0524x over previous
//
#include <hip/hip_runtime.h>
#include <hip/hip_bf16.h>

#define IN_DIM 128
#define OUT_DIM 64
#define NPB_LOG 9                  // 512 nodes per bucket
#define NPB (1 << NPB_LOG)
#define MAXBUCK 1024               // supports n_nodes <= 512K
#define B1 1024                    // bucketing blocks (kA/kB); must match between them
#define SCAN_TPB 256

static inline size_t align_up(size_t v, size_t a) { return (v + a - 1) & ~(a - 1); }

__device__ __forceinline__ float bf2f(unsigned short u) {
    return __uint_as_float(((unsigned int)u) << 16);
}
__device__ __forceinline__ unsigned short f2bf(float f) {
    unsigned int x = __float_as_uint(f);
    unsigned int r = (x + 0x7fffu + ((x >> 16) & 1u)) >> 16;  // RTNE
    return (unsigned short)r;
}

typedef _Float16 half8 __attribute__((ext_vector_type(8)));
typedef float f32x4 __attribute__((ext_vector_type(4)));

// ---------------------------------------------------------------------------
// kA: per-block LDS histogram of col>>9 -> Hist[blk][bin]
// ---------------------------------------------------------------------------
__global__ void __launch_bounds__(256) kA_count(
    const int* __restrict__ col, int* __restrict__ Hist,
    int n_edges, int nbuck, int chunk) {
    __shared__ int hist[MAXBUCK];
    for (int i = threadIdx.x; i < nbuck; i += 256) hist[i] = 0;
    __syncthreads();
    int start = blockIdx.x * chunk;
    int end = min(n_edges, start + chunk);
    for (int i = start + threadIdx.x; i < end; i += 256)
        atomicAdd(&hist[col[i] >> NPB_LOG], 1);
    __syncthreads();
    int* hrow = Hist + (size_t)blockIdx.x * nbuck;
    for (int i = threadIdx.x; i < nbuck; i += 256) hrow[i] = hist[i];
}

// ---------------------------------------------------------------------------
// kS1: per-bin exclusive scan over blocks: Offs[blk][bin], BinTotal[bin]
// ---------------------------------------------------------------------------
__global__ void __launch_bounds__(256) kS1_scanbins(
    const int* __restrict__ Hist, int* __restrict__ Offs,
    int* __restrict__ BinTotal, int nbuck) {
    __shared__ int s[SCAN_TPB];
    int bin = blockIdx.x;
    int t = threadIdx.x;
    int v[4];
#pragma unroll
    for (int j = 0; j < 4; ++j) v[j] = Hist[(size_t)(t * 4 + j) * nbuck + bin];
    int tsum = v[0] + v[1] + v[2] + v[3];
    s[t] = tsum;
    __syncthreads();
    for (int off = 1; off < SCAN_TPB; off <<= 1) {
        int x = (t >= off) ? s[t - off] : 0;
        __syncthreads();
        s[t] += x;
        __syncthreads();
    }
    int run = s[t] - tsum;  // exclusive prefix
#pragma unroll
    for (int j = 0; j < 4; ++j) {
        Offs[(size_t)(t * 4 + j) * nbuck + bin] = run;
        run += v[j];
    }
    if (t == SCAN_TPB - 1) BinTotal[bin] = run;
}

// ---------------------------------------------------------------------------
// kS2: exclusive scan of BinTotal -> BucketStart[nbuck+1]; sentinels
// ---------------------------------------------------------------------------
__global__ void __launch_bounds__(256) kS2_scantotals(
    const int* __restrict__ BinTotal, int* __restrict__ BucketStart,
    int* __restrict__ row_start, int nbuck, int n_nodes, int n_edges) {
    __shared__ int s[SCAN_TPB];
    int t = threadIdx.x;
    int v[4];
#pragma unroll
    for (int j = 0; j < 4; ++j) {
        int idx = t * 4 + j;
        v[j] = (idx < nbuck) ? BinTotal[idx] : 0;
    }
    int tsum = v[0] + v[1] + v[2] + v[3];
    s[t] = tsum;
    __syncthreads();
    for (int off = 1; off < SCAN_TPB; off <<= 1) {
        int x = (t >= off) ? s[t - off] : 0;
        __syncthreads();
        s[t] += x;
        __syncthreads();
    }
    int run = s[t] - tsum;
#pragma unroll
    for (int j = 0; j < 4; ++j) {
        int idx = t * 4 + j;
        if (idx < nbuck) BucketStart[idx] = run;
        run += v[j];
    }
    if (t == 0) {
        BucketStart[nbuck] = n_edges;
        row_start[n_nodes] = n_edges;
    }
}

// ---------------------------------------------------------------------------
// kB: scatter edges to bucket regions, packed (row<<9)|(col&511); LDS cursors
// ---------------------------------------------------------------------------
__global__ void __launch_bounds__(256) kB_scatter(
    const int* __restrict__ row, const int* __restrict__ col,
    const int* __restrict__ BucketStart, const int* __restrict__ Offs,
    unsigned int* __restrict__ EdgeBuf, int n_edges, int nbuck, int chunk) {
    __shared__ int cur[MAXBUCK];
    const int* orow = Offs + (size_t)blockIdx.x * nbuck;
    for (int i = threadIdx.x; i < nbuck; i += 256)
        cur[i] = BucketStart[i] + orow[i];
    __syncthreads();
    int start = blockIdx.x * chunk;
    int end = min(n_edges, start + chunk);
    for (int i = start + threadIdx.x; i < end; i += 256) {
        int c = col[i];
        int r = row[i];
        int bin = c >> NPB_LOG;
        int p = atomicAdd(&cur[bin], 1);
        EdgeBuf[p] = ((unsigned int)r << NPB_LOG) | (unsigned int)(c & (NPB - 1));
    }
}

// ---------------------------------------------------------------------------
// kC: per-bucket in-LDS counting sort -> row_start, dis (fused rsqrt), edge_src
// ---------------------------------------------------------------------------
__global__ void __launch_bounds__(256) kC_localsort(
    const unsigned int* __restrict__ EdgeBuf, const int* __restrict__ BucketStart,
    int* __restrict__ row_start, float* __restrict__ dis,
    int* __restrict__ edge_src, int n_nodes) {
    __shared__ int cnt[NPB];
    __shared__ int cur[NPB];
    __shared__ int s[SCAN_TPB];
    int t = threadIdx.x;
    int nb0 = blockIdx.x << NPB_LOG;
    int nn = min(NPB, n_nodes - nb0);
    int es = BucketStart[blockIdx.x];
    int ee = BucketStart[blockIdx.x + 1];

    for (int i = t; i < NPB; i += 256) cnt[i] = 0;
    __syncthreads();
    for (int i = es + t; i < ee; i += 256)
        atomicAdd(&cnt[EdgeBuf[i] & (NPB - 1)], 1);
    __syncthreads();

    int a = cnt[2 * t];
    int b = cnt[2 * t + 1];
    int tsum = a + b;
    s[t] = tsum;
    __syncthreads();
    for (int off = 1; off < SCAN_TPB; off <<= 1) {
        int x = (t >= off) ? s[t - off] : 0;
        __syncthreads();
        s[t] += x;
        __syncthreads();
    }
    int excl = s[t] - tsum;
    if (2 * t < nn) {
        row_start[nb0 + 2 * t] = es + excl;
        dis[nb0 + 2 * t] = (a > 0) ? rsqrtf((float)a) : 0.0f;
    }
    if (2 * t + 1 < nn) {
        row_start[nb0 + 2 * t + 1] = es + excl + a;
        dis[nb0 + 2 * t + 1] = (b > 0) ? rsqrtf((float)b) : 0.0f;
    }
    cur[2 * t] = excl;
    cur[2 * t + 1] = excl + a;
    __syncthreads();

    for (int i = es + t; i < ee; i += 256) {
        unsigned int v = EdgeBuf[i];
        int cl = v & (NPB - 1);
        int r = (int)(v >> NPB_LOG);
        int p = atomicAdd(&cur[cl], 1);
        edge_src[es + p] = r;
    }
}

// ---------------------------------------------------------------------------
// k_matmul_mfma: h(bf16) = (x @ W) * dis via f16 MFMA 16x16x32.
// One wave per 16-node tile; W fragments hoisted; no LDS/barriers.
// ---------------------------------------------------------------------------
__global__ void __launch_bounds__(256) k_matmul_mfma(
    const float* __restrict__ x, const float* __restrict__ W,
    const float* __restrict__ dis, unsigned short* __restrict__ h, int n_nodes) {
    const int lane = threadIdx.x & 63;
    const int m = lane & 15;       // A-row / D-col index
    const int q = lane >> 4;       // quad
    const int wid = (blockIdx.x * blockDim.x + threadIdx.x) >> 6;
    const int ntiles = (n_nodes + 15) >> 4;
    if (wid >= ntiles) return;

    half8 bfrag[4][4];
#pragma unroll
    for (int kt = 0; kt < 4; ++kt) {
#pragma unroll
        for (int nt = 0; nt < 4; ++nt) {
            int k0 = kt * 32 + q * 8;
            int c = nt * 16 + m;
#pragma unroll
            for (int j = 0; j < 8; ++j)
                bfrag[kt][nt][j] = (_Float16)W[(size_t)(k0 + j) * OUT_DIM + c];
        }
    }

    const int nb = wid << 4;
    int arow = nb + m;
    if (arow >= n_nodes) arow = n_nodes - 1;
    const float* xr = x + (size_t)arow * IN_DIM;

    f32x4 acc[4];
#pragma unroll
    for (int nt = 0; nt < 4; ++nt) acc[nt] = (f32x4){0.f, 0.f, 0.f, 0.f};

#pragma unroll
    for (int kt = 0; kt < 4; ++kt) {
        const float4* xp = (const float4*)(xr + kt * 32 + q * 8);
        float4 lo = xp[0];
        float4 hi = xp[1];
        half8 afrag;
        afrag[0] = (_Float16)lo.x; afrag[1] = (_Float16)lo.y;
        afrag[2] = (_Float16)lo.z; afrag[3] = (_Float16)lo.w;
        afrag[4] = (_Float16)hi.x; afrag[5] = (_Float16)hi.y;
        afrag[6] = (_Float16)hi.z; afrag[7] = (_Float16)hi.w;
#pragma unroll
        for (int nt = 0; nt < 4; ++nt)
            acc[nt] = __builtin_amdgcn_mfma_f32_16x16x32_f16(afrag, bfrag[kt][nt],
                                                             acc[nt], 0, 0, 0);
    }

#pragma unroll
    for (int r = 0; r < 4; ++r) {
        int node = nb + q * 4 + r;
        if (node < n_nodes) {
            float dv = dis[node];
            unsigned short* hp = h + (size_t)node * OUT_DIM + m;
#pragma unroll
            for (int nt = 0; nt < 4; ++nt)
                hp[nt * 16] = f2bf(acc[nt][r] * dv);
        }
    }
}

// ---------------------------------------------------------------------------
// k_aggregate: out[c] = relu(dis[c] * sum h[r] + b); wave per target node.
// 4 edges in flight per wave (one per quarter-wave, uint2 = 4 bf16 cols each),
// unrolled x2. Shfls are executed UNCONDITIONALLY by all 64 lanes with a
// clamped source index (ds_bpermute from an exec-masked-off lane is
// undefined -- that was round 7's bug); only the gather load is predicated.
// ---------------------------------------------------------------------------
__global__ void __launch_bounds__(256) k_aggregate(
    const int* __restrict__ row_start, const int* __restrict__ edge_src,
    const float* __restrict__ dis, const unsigned short* __restrict__ h,
    const float* __restrict__ b, float* __restrict__ out,
    int n_nodes, int n_edges) {
    const int lane = threadIdx.x & 63;
    const int quarter = lane >> 4;      // 0..3: which edge of a 4-group
    const int qlane = lane & 15;        // 16 lanes cover 64 cols (4 each)
    int wid = (blockIdx.x * blockDim.x + threadIdx.x) >> 6;
    int nw = (gridDim.x * blockDim.x) >> 6;
    float4 bias = ((const float4*)b)[qlane];

    for (int c = wid; c < n_nodes; c += nw) {
        int s = row_start[c];
        int e = row_start[c + 1];
        float a0 = 0.f, a1 = 0.f, a2 = 0.f, a3 = 0.f;
        for (int base = s; base < e; base += 64) {
            int li = base + lane;
            int eidx = edge_src[(li < n_edges) ? li : (n_edges - 1)];  // coalesced
            int cnt = min(64, e - base);
            for (int j = 0; j < cnt; j += 8) {                // wave-uniform loop
                int iA = j + quarter;
                int iB = j + 4 + quarter;
                // shfl with all lanes active; clamp source to a valid lane
                int sA = (iA < cnt) ? iA : 0;
                int sB = (iB < cnt) ? iB : 0;
                int rA = __shfl(eidx, sA, 64);
                int rB = __shfl(eidx, sB, 64);
                uint2 vA = make_uint2(0u, 0u), vB = make_uint2(0u, 0u);
                if (iA < cnt)
                    vA = *(const uint2*)(h + (size_t)rA * OUT_DIM + qlane * 4);
                if (iB < cnt)
                    vB = *(const uint2*)(h + (size_t)rB * OUT_DIM + qlane * 4);
                a0 += __uint_as_float(vA.x << 16);
                a1 += __uint_as_float(vA.x & 0xFFFF0000u);
                a2 += __uint_as_float(vA.y << 16);
                a3 += __uint_as_float(vA.y & 0xFFFF0000u);
                a0 += __uint_as_float(vB.x << 16);
                a1 += __uint_as_float(vB.x & 0xFFFF0000u);
                a2 += __uint_as_float(vB.y << 16);
                a3 += __uint_as_float(vB.y & 0xFFFF0000u);
            }
        }
        // reduce across the 4 quarters (all lanes active here)
        a0 += __shfl_xor(a0, 16, 64); a0 += __shfl_xor(a0, 32, 64);
        a1 += __shfl_xor(a1, 16, 64); a1 += __shfl_xor(a1, 32, 64);
        a2 += __shfl_xor(a2, 16, 64); a2 += __shfl_xor(a2, 32, 64);
        a3 += __shfl_xor(a3, 16, 64); a3 += __shfl_xor(a3, 32, 64);
        if (quarter == 0) {
            float dv = dis[c];
            float4 o;
            o.x = fmaxf(fmaf(a0, dv, bias.x), 0.f);
            o.y = fmaxf(fmaf(a1, dv, bias.y), 0.f);
            o.z = fmaxf(fmaf(a2, dv, bias.z), 0.f);
            o.w = fmaxf(fmaf(a3, dv, bias.w), 0.f);
            ((float4*)(out + (size_t)c * OUT_DIM))[qlane] = o;
        }
    }
}

// ---------------------------------------------------------------------------
// Fallback path (exotic sizes / small workspace): atomic scatter, fp32 h
// ---------------------------------------------------------------------------
#define MM_NODES 16
__global__ void __launch_bounds__(256) k_matmul_f32(
    const float* __restrict__ x, const float* __restrict__ W,
    const float* __restrict__ dis, float* __restrict__ h, int n_nodes) {
    __shared__ float xs[MM_NODES * IN_DIM];
    const int lane = threadIdx.x & 63;
    const int wv = threadIdx.x >> 6;
    float w[IN_DIM];
#pragma unroll
    for (int k = 0; k < IN_DIM; ++k) w[k] = W[k * OUT_DIM + lane];
    int nchunks = (n_nodes + MM_NODES - 1) / MM_NODES;
    for (int ch = blockIdx.x; ch < nchunks; ch += gridDim.x) {
        int base = ch * MM_NODES;
        int nrows = min(MM_NODES, n_nodes - base);
        __syncthreads();
        const float4* xg = (const float4*)(x + (size_t)base * IN_DIM);
        int nf4 = nrows * IN_DIM / 4;
        for (int i = threadIdx.x; i < nf4; i += 256) ((float4*)xs)[i] = xg[i];
        __syncthreads();
#pragma unroll
        for (int j = 0; j < 4; ++j) {
            int local = wv * 4 + j;
            int node = base + local;
            if (local < nrows) {
                const float4* xr = (const float4*)(xs + local * IN_DIM);
                float acc = 0.0f;
#pragma unroll
                for (int k4 = 0; k4 < IN_DIM / 4; ++k4) {
                    float4 xv = xr[k4];
                    acc = fmaf(xv.x, w[k4 * 4 + 0], acc);
                    acc = fmaf(xv.y, w[k4 * 4 + 1], acc);
                    acc = fmaf(xv.z, w[k4 * 4 + 2], acc);
                    acc = fmaf(xv.w, w[k4 * 4 + 3], acc);
                }
                h[(size_t)node * OUT_DIM + lane] = acc * dis[node];
            }
        }
    }
}

__global__ void k_degree_fb(const int* __restrict__ col, int* __restrict__ deg,
                            int n_edges) {
    int i = blockIdx.x * blockDim.x + threadIdx.x;
    int stride = gridDim.x * blockDim.x;
    for (; i < n_edges; i += stride) atomicAdd(&deg[col[i]], 1);
}

__global__ void k_rsqrt_fb(const int* __restrict__ deg, float* __restrict__ dis, int n) {
    int i = blockIdx.x * blockDim.x + threadIdx.x;
    if (i < n) {
        int d = deg[i];
        dis[i] = (d > 0) ? rsqrtf((float)d) : 0.0f;
    }
}

__global__ void __launch_bounds__(256) k_scatter_fb(
    const int* __restrict__ row, const int* __restrict__ col,
    const float* __restrict__ dis, const float* __restrict__ h,
    float* __restrict__ out, int n_edges) {
    const int lane = threadIdx.x & 63;
    int e = (blockIdx.x * blockDim.x + threadIdx.x) >> 6;
    int nw = (gridDim.x * blockDim.x) >> 6;
    for (; e < n_edges; e += nw) {
        int r = row[e];
        int c = col[e];
        float v = h[(size_t)r * OUT_DIM + lane] * dis[c];
        atomicAdd(&out[(size_t)c * OUT_DIM + lane], v);
    }
}

__global__ void k_bias_relu_fb(float* __restrict__ out, const float* __restrict__ b,
                               int total) {
    int i = blockIdx.x * blockDim.x + threadIdx.x;
    int stride = gridDim.x * blockDim.x;
    for (; i < total; i += stride) {
        float v = out[i] + b[i & (OUT_DIM - 1)];
        out[i] = fmaxf(v, 0.0f);
    }
}

extern "C" void kernel_launch(void* const* d_in, const int* in_sizes, int n_in,
                              void* d_out, int out_size, void* d_ws, size_t ws_size,
                              hipStream_t stream) {
    const float* x = (const float*)d_in[0];
    const int* ei = (const int*)d_in[1];  // [2, E] int32
    const float* W = (const float*)d_in[2];
    const float* b = (const float*)d_in[3];
    float* out = (float*)d_out;

    const int n_nodes = in_sizes[0] / IN_DIM;
    const int n_edges = in_sizes[1] / 2;
    const int* row = ei;
    const int* col = ei + n_edges;

    const int nbuck = (n_nodes + NPB - 1) >> NPB_LOG;
    const int chunk = (n_edges + B1 - 1) / B1;

    // ---- workspace layout ----
    char* wsb = (char*)d_ws;
    size_t off = 0;
    int* Hist = (int*)(wsb + off);       off += align_up((size_t)B1 * nbuck * 4, 256);
    int* Offs = (int*)(wsb + off);       off += align_up((size_t)B1 * nbuck * 4, 256);
    int* BinTotal = (int*)(wsb + off);   off += align_up((size_t)nbuck * 4, 256);
    int* BucketStart = (int*)(wsb + off);off += align_up((size_t)(nbuck + 1) * 4, 256);
    int* row_start = (int*)(wsb + off);  off += align_up((size_t)(n_nodes + 1) * 4, 256);
    float* dis = (float*)(wsb + off);    off += align_up((size_t)n_nodes * 4, 256);
    unsigned int* EdgeBuf = (unsigned int*)(wsb + off);
                                         off += align_up((size_t)n_edges * 4, 256);
    int* edge_src = (int*)(wsb + off);   off += align_up((size_t)n_edges * 4, 256);
    unsigned short* h = (unsigned short*)(wsb + off);
                                         off += (size_t)n_nodes * OUT_DIM * 2;
    const size_t needed = off;

    const bool ok = (ws_size >= needed) && (nbuck <= MAXBUCK) &&
                    (n_nodes <= (1 << 23));

    if (ok) {
        kA_count<<<B1, 256, 0, stream>>>(col, Hist, n_edges, nbuck, chunk);
        kS1_scanbins<<<nbuck, 256, 0, stream>>>(Hist, Offs, BinTotal, nbuck);
        kS2_scantotals<<<1, 256, 0, stream>>>(BinTotal, BucketStart, row_start,
                                              nbuck, n_nodes, n_edges);
        kB_scatter<<<B1, 256, 0, stream>>>(row, col, BucketStart, Offs, EdgeBuf,
                                           n_edges, nbuck, chunk);
        kC_localsort<<<nbuck, 256, 0, stream>>>(EdgeBuf, BucketStart, row_start,
                                                dis, edge_src, n_nodes);
        int ntiles = (n_nodes + 15) / 16;           // one wave per 16 nodes
        int mm_blocks = (ntiles + 3) / 4;           // 4 waves per block
        k_matmul_mfma<<<mm_blocks, 256, 0, stream>>>(x, W, dis, h, n_nodes);
        int agg_blocks = (n_nodes + 3) / 4 + 1;     // one wave per node
        k_aggregate<<<agg_blocks, 256, 0, stream>>>(row_start, edge_src, dis, h, b,
                                                    out, n_nodes, n_edges);
    } else {
        // ---- fallback: atomic scatter, fp32 h ----
        char* p = (char*)d_ws;
        int* deg_f = (int*)p;
        float* dis_f = (float*)(p + align_up((size_t)n_nodes * 4, 256));
        float* h_f = (float*)(p + 2 * align_up((size_t)n_nodes * 4, 256));
        hipMemsetAsync(deg_f, 0, (size_t)n_nodes * 4, stream);
        hipMemsetAsync(out, 0, (size_t)out_size * 4, stream);
        k_degree_fb<<<1024, 256, 0, stream>>>(col, deg_f, n_edges);
        k_rsqrt_fb<<<(n_nodes + 255) / 256, 256, 0, stream>>>(deg_f, dis_f, n_nodes);
        k_matmul_f32<<<1024, 256, 0, stream>>>(x, W, dis_f, h_f, n_nodes);
        k_scatter_fb<<<2048, 256, 0, stream>>>(row, col, dis_f, h_f, out, n_edges);
        k_bias_relu_fb<<<2048, 256, 0, stream>>>(out, b, n_nodes * OUT_DIM);
    }
}